// Round 15
// baseline (118.830 us; speedup 1.0000x reference)
//
#include <hip/hip_runtime.h>
#include <math.h>

#define N_NEU 256
#define D_DIM 32
#define KFD   16
#define KN    50
#define B_SZ  512
#define UINF  128
#define GAMMA 0.1f
#define DT    0.05f
#define NSTEP 20

#define TBL_K   4096
#define TBL_LO  (-64.0f)
#define TBL_IDL 32.0f          // 1/Delta ; Delta = 1/32, range [-64, +64)

#define TOPK_BLKS  N_NEU                 // 256
#define TBL_BLKS   (TBL_K * 32 / 256)    // 512

typedef __attribute__((ext_vector_type(8))) short bf16x8;
typedef __attribute__((ext_vector_type(4))) float f32x4;

__device__ __forceinline__ unsigned short f2bf(float f) {
    unsigned u = __float_as_uint(f);
    u += 0x7FFFu + ((u >> 16) & 1u);     // round-to-nearest-even
    return (unsigned short)(u >> 16);
}
__device__ __forceinline__ float bf_lo(unsigned q) { return __uint_as_float(q << 16); }
__device__ __forceinline__ float bf_hi(unsigned q) { return __uint_as_float(q & 0xFFFF0000u); }

__device__ __forceinline__ bf16x8 pack8(float4 a0, float4 a1) {
    bf16x8 f;
    f[0] = (short)f2bf(a0.x); f[1] = (short)f2bf(a0.y);
    f[2] = (short)f2bf(a0.z); f[3] = (short)f2bf(a0.w);
    f[4] = (short)f2bf(a1.x); f[5] = (short)f2bf(a1.y);
    f[6] = (short)f2bf(a1.z); f[7] = (short)f2bf(a1.w);
    return f;
}

// ---------------------------------------------------------------------------
// Kernel A: topk [0,256) + mlp table [256,768).
// vals now in QUARTER-13 layout: val4T[j<13][n*4+s] covering k = s*13 + j,
// zero-padded to 52 (k=50,51 -> s=3, j=11,12).
// ---------------------------------------------------------------------------
__global__ __launch_bounds__(256) void pre_kernel(const float* __restrict__ features,
                                                  const float* __restrict__ sig_w1,
                                                  const float* __restrict__ sig_b1,
                                                  const float* __restrict__ sig_w2,
                                                  int* __restrict__ idxT,
                                                  float* __restrict__ val4T,
                                                  unsigned int* __restrict__ tbl) {
    __shared__ float fsh[N_NEU][KFD + 1];
    __shared__ float sim_sh[N_NEU];

    const int bid = blockIdx.x;

    if (bid < TOPK_BLKS) {
        // ---- topk ----
        const int n = bid;
        const int j = threadIdx.x;

        float v[KFD];
        float s = 0.f;
#pragma unroll
        for (int d = 0; d < KFD; ++d) { v[d] = features[j * KFD + d]; s = fmaf(v[d], v[d], s); }
        const float nrm = sqrtf(s);
#pragma unroll
        for (int d = 0; d < KFD; ++d) fsh[j][d] = v[d] / nrm;
        __syncthreads();

        float dot = 0.f;
#pragma unroll
        for (int d = 0; d < KFD; ++d) dot = fmaf(fsh[n][d], fsh[j][d], dot);
        sim_sh[j] = dot;
        __syncthreads();

        if (j < 64) {
            float l0 = sim_sh[j];
            float l1 = sim_sh[j + 64];
            float l2 = sim_sh[j + 128];
            float l3 = sim_sh[j + 192];
            for (int k = 0; k < KN; ++k) {
                float bv = l0; int bi = j;
                if (l1 > bv) { bv = l1; bi = j + 64; }
                if (l2 > bv) { bv = l2; bi = j + 128; }
                if (l3 > bv) { bv = l3; bi = j + 192; }
                for (int off = 32; off > 0; off >>= 1) {
                    float ov = __shfl_xor(bv, off, 64);
                    int   oi = __shfl_xor(bi, off, 64);
                    if (ov > bv || (ov == bv && oi < bi)) { bv = ov; bi = oi; }
                }
                if (j == 0) {
                    const int s_ = k / 13;
                    const int r_ = k - 13 * s_;
                    val4T[r_ * 1024 + n * 4 + s_] = bv;
                    idxT[k * N_NEU + n] = bi;
                }
                if ((bi & 63) == j) {
                    const int q = bi >> 6;
                    if      (q == 0) l0 = -INFINITY;
                    else if (q == 1) l1 = -INFINITY;
                    else if (q == 2) l2 = -INFINITY;
                    else             l3 = -INFINITY;
                }
            }
            if (j == 0) {   // zero-pad k = 50,51 (s=3, r=11,12)
                val4T[11 * 1024 + n * 4 + 3] = 0.f;
                val4T[12 * 1024 + n * 4 + 3] = 0.f;
            }
        }
    } else {
        // ---- mlp table ----
        const int gid = (bid - TOPK_BLKS) * 256 + threadIdx.x;  // k*32+d
        const int k = gid >> 5, d = gid & 31;
        const float s0 = TBL_LO + (float)k / TBL_IDL;
        const float s1 = s0 + 1.0f / TBL_IDL;
        float g0 = 0.f, g1 = 0.f;
#pragma unroll
        for (int j = 0; j < 16; ++j) {
            const float w1 = sig_w1[j], b1 = sig_b1[j], w2 = sig_w2[d * 16 + j];
            const float h0 = fmaf(s0, w1, b1);
            const float h1 = fmaf(s1, w1, b1);
            const float e0 = 0.5f * h0 * (1.0f + erff(h0 * 0.70710678118654752f));
            const float e1 = 0.5f * h1 * (1.0f + erff(h1 * 0.70710678118654752f));
            g0 = fmaf(e0, w2, g0);
            g1 = fmaf(e1, w2, g1);
        }
        g0 *= DT; g1 *= DT;
        tbl[gid] = (unsigned int)f2bf(g0) | ((unsigned int)f2bf(g1 - g0) << 16);
    }
}

// ---------------------------------------------------------------------------
// Kernel B: fused uproj-GEMM + 20-step recurrence.
// r14 lesson: grid was 256 blocks on 256 CUs — a 2nd co-resident block was
// arithmetically impossible. This round: grid 512 x 1024, ONE batch/block,
// 4 subthreads/neuron (s=t&3: 8 dims + 13 gathers each). LDS = 38,912 B
// (cdt_sh 1 batch + a_sh) -> TWO blocks/CU = two independent barrier
// domains interleaving phases; 32 waves/CU. VGPR ~54 (x8+ccdt8+vv13+gp13)
// under the (1024,4) 64-reg cap that r14 verified spill-free.
// ---------------------------------------------------------------------------
__global__ __launch_bounds__(1024, 4) void steps_kernel(const float* __restrict__ u,
                                                        const float* __restrict__ w_in,
                                                        const float* __restrict__ b_in,
                                                        const float* __restrict__ bias,
                                                        const float* __restrict__ sig_b2,
                                                        const int* __restrict__ idxT,
                                                        const float* __restrict__ val4T,
                                                        const unsigned int* __restrict__ tbl,
                                                        float* __restrict__ out) {
    __shared__ float cdt_sh[256 * 36];             // 36864 B, row stride 36 (pad 4)
    __shared__ float a_sh[2 * N_NEU];              // 2048 B

    const int t = threadIdx.x;
    const int b = blockIdx.x;

    // ---- phase 0: per-wave 16-row GEMM (w_in fragments straight from L2) ----
    {
        const int wave = t >> 6;                       // 16 waves x 16 rows = 256
        const int lane = t & 63;
        const int row  = lane & 15;
        const int kg   = lane >> 4;
        const int wrow = wave * 16;

        bf16x8 bfrag[2][4];
#pragma unroll
        for (int dt_ = 0; dt_ < 2; ++dt_) {
#pragma unroll
            for (int kk = 0; kk < 4; ++kk) {
                const float* wp = w_in + (dt_ * 16 + row) * UINF + kk * 32 + kg * 8;
                const float4 w0 = *reinterpret_cast<const float4*>(wp);
                const float4 w1 = *reinterpret_cast<const float4*>(wp + 4);
                bfrag[dt_][kk] = pack8(w0, w1);
            }
        }

        const float* ub = u + ((long)b * N_NEU + wrow + row) * UINF + kg * 8;
        float4 L[8];
#pragma unroll
        for (int kk = 0; kk < 4; ++kk) {
            L[kk * 2 + 0] = *reinterpret_cast<const float4*>(ub + kk * 32);
            L[kk * 2 + 1] = *reinterpret_cast<const float4*>(ub + kk * 32 + 4);
        }
        f32x4 a0 = {0.f, 0.f, 0.f, 0.f};
        f32x4 a1 = {0.f, 0.f, 0.f, 0.f};
#pragma unroll
        for (int kk = 0; kk < 4; ++kk) {
            const bf16x8 af = pack8(L[kk * 2], L[kk * 2 + 1]);
            a0 = __builtin_amdgcn_mfma_f32_16x16x32_bf16(af, bfrag[0][kk], a0, 0, 0, 0);
            a1 = __builtin_amdgcn_mfma_f32_16x16x32_bf16(af, bfrag[1][kk], a1, 0, 0, 0);
        }
        const int   d0   = row;
        const int   d1   = 16 + row;
        const float add0 = b_in[d0] + sig_b2[d0];
        const float add1 = b_in[d1] + sig_b2[d1];
#pragma unroll
        for (int r = 0; r < 4; ++r) {
            const int nl = wrow + kg * 4 + r;
            cdt_sh[nl * 36 + d0] = DT * (a0[r] + add0 + bias[nl * D_DIM + d0]);
            cdt_sh[nl * 36 + d1] = DT * (a1[r] + add1 + bias[nl * D_DIM + d1]);
        }
    }
    __syncthreads();

    // ---- per-thread mapping: neuron n, subthread s (8 dims, 13 gathers) ----
    const int n = t >> 2;
    const int s = t & 3;

    float ccdt[8];
    {
        const float* cbase = &cdt_sh[n * 36 + s * 8];
#pragma unroll
        for (int i = 0; i < 2; ++i) {
            const float4 cv = *reinterpret_cast<const float4*>(cbase + i * 4);
            ccdt[4 * i + 0] = cv.x; ccdt[4 * i + 1] = cv.y;
            ccdt[4 * i + 2] = cv.z; ccdt[4 * i + 3] = cv.w;
        }
    }

    // step-invariant per-thread vals (13 f32 regs) + gather pointers (13 LDS ptrs)
    float vvv[13];
#pragma unroll
    for (int j = 0; j < 13; ++j) vvv[j] = val4T[j * 1024 + t];

    const float* gp[13];
#pragma unroll
    for (int j = 0; j < 13; ++j) {
        const int k = s * 13 + j;
        const int ii = (k < KN) ? idxT[k * N_NEU + n] : 0;
        gp[j] = &a_sh[ii];
    }

    float x[8];
#pragma unroll
    for (int d = 0; d < 8; ++d) x[d] = 0.f;

    const float K1 = 1.0f - DT * GAMMA;   // 0.995

#define STEP_BODY(BUF)                                                          \
    {                                                                           \
        float nh = 0.f;                                                         \
        _Pragma("unroll")                                                       \
        for (int d = 0; d < 8; ++d) nh = fmaf(x[d], x[d], nh);                  \
        float nfull = nh + __shfl_xor(nh, 1, 64);                               \
        nfull += __shfl_xor(nfull, 2, 64);                                      \
        nfull += 1e-12f;                                                        \
        const float z = sqrtf(nfull);                                           \
        const float a = 1.0f - 2.0f / (__expf(2.0f * z) + 1.0f);                \
        if (s == 0) a_sh[(BUF) * N_NEU + n] = a;                                \
        _Pragma("unroll")                                                       \
        for (int d = 0; d < 8; ++d) x[d] = fmaf(K1, x[d], ccdt[d]);             \
        __syncthreads();                                                        \
        float s0 = 0.f, s1 = 0.f;                                               \
        _Pragma("unroll")                                                       \
        for (int j = 0; j < 13; ++j) {                                          \
            const float av = gp[j][(BUF) * N_NEU];                              \
            if (j & 1) s1 = fmaf(av, vvv[j], s1);                               \
            else       s0 = fmaf(av, vvv[j], s0);                               \
        }                                                                       \
        float syn = s0 + s1;                                                    \
        syn += __shfl_xor(syn, 1, 64);                                          \
        syn += __shfl_xor(syn, 2, 64);                                          \
        const float uu = fmaf(syn, TBL_IDL, -TBL_LO * TBL_IDL);                 \
        int i = (int)uu;                                                        \
        i = (i < 0) ? 0 : (i > TBL_K - 2 ? TBL_K - 2 : i);                      \
        const float tf = uu - (float)i;                                         \
        const uint4* rp = reinterpret_cast<const uint4*>(tbl + (size_t)i * 32 + s * 8); \
        _Pragma("unroll")                                                       \
        for (int c = 0; c < 2; ++c) {                                           \
            const uint4 q = rp[c];                                              \
            x[4 * c + 0] = fmaf(tf, bf_hi(q.x), x[4 * c + 0] + bf_lo(q.x));     \
            x[4 * c + 1] = fmaf(tf, bf_hi(q.y), x[4 * c + 1] + bf_lo(q.y));     \
            x[4 * c + 2] = fmaf(tf, bf_hi(q.z), x[4 * c + 2] + bf_lo(q.z));     \
            x[4 * c + 3] = fmaf(tf, bf_hi(q.w), x[4 * c + 3] + bf_lo(q.w));     \
        }                                                                       \
    }

    for (int it = 0; it < NSTEP / 2; ++it) {
        STEP_BODY(0);
        STEP_BODY(1);
    }
#undef STEP_BODY

    float4* op4 = reinterpret_cast<float4*>(out + ((size_t)b * N_NEU + n) * D_DIM + s * 8);
    op4[0] = make_float4(x[0], x[1], x[2], x[3]);
    op4[1] = make_float4(x[4], x[5], x[6], x[7]);
}

extern "C" void kernel_launch(void* const* d_in, const int* in_sizes, int n_in,
                              void* d_out, int out_size, void* d_ws, size_t ws_size,
                              hipStream_t stream) {
    const float* u        = (const float*)d_in[0];
    const float* features = (const float*)d_in[1];
    const float* bias     = (const float*)d_in[2];
    const float* w_in     = (const float*)d_in[3];
    const float* b_in     = (const float*)d_in[4];
    const float* sig_w1   = (const float*)d_in[5];
    const float* sig_b1   = (const float*)d_in[6];
    const float* sig_w2   = (const float*)d_in[7];
    const float* sig_b2   = (const float*)d_in[8];
    float* out = (float*)d_out;

    char*         ws     = (char*)d_ws;
    int*          idxT   = (int*)ws;                      // 51200 B
    float*        val4T  = (float*)(ws + 51200);          // 13*1024*4 = 53248 B
    unsigned int* tbl    = (unsigned int*)(ws + 104448);  // 512 KiB

    hipLaunchKernelGGL(pre_kernel, dim3(TOPK_BLKS + TBL_BLKS), dim3(256), 0, stream,
                       features, sig_w1, sig_b1, sig_w2, idxT, val4T, tbl);
    hipLaunchKernelGGL(steps_kernel, dim3(B_SZ), dim3(1024), 0, stream,
                       u, w_in, b_in, bias, sig_b2, idxT, val4T, tbl, out);
}

// Round 16
// 113.471 us; speedup vs baseline: 1.0472x; 1.0472x over previous
//
#include <hip/hip_runtime.h>
#include <math.h>

#define N_NEU 256
#define D_DIM 32
#define KFD   16
#define KN    50
#define B_SZ  512
#define UINF  128
#define GAMMA 0.1f
#define DT    0.05f
#define NSTEP 20

#define TBL_K   4096
#define TBL_LO  (-64.0f)
#define TBL_IDL 32.0f          // 1/Delta ; Delta = 1/32, range [-64, +64)

#define TOPK_BLKS  N_NEU                 // 256
#define TBL_BLKS   (TBL_K * 32 / 256)    // 512

typedef __attribute__((ext_vector_type(8))) short bf16x8;
typedef __attribute__((ext_vector_type(4))) float f32x4;

__device__ __forceinline__ unsigned short f2bf(float f) {
    unsigned u = __float_as_uint(f);
    u += 0x7FFFu + ((u >> 16) & 1u);     // round-to-nearest-even
    return (unsigned short)(u >> 16);
}
__device__ __forceinline__ float bf_lo(unsigned q) { return __uint_as_float(q << 16); }
__device__ __forceinline__ float bf_hi(unsigned q) { return __uint_as_float(q & 0xFFFF0000u); }

__device__ __forceinline__ bf16x8 pack8(float4 a0, float4 a1) {
    bf16x8 f;
    f[0] = (short)f2bf(a0.x); f[1] = (short)f2bf(a0.y);
    f[2] = (short)f2bf(a0.z); f[3] = (short)f2bf(a0.w);
    f[4] = (short)f2bf(a1.x); f[5] = (short)f2bf(a1.y);
    f[6] = (short)f2bf(a1.z); f[7] = (short)f2bf(a1.w);
    return f;
}

// ---------------------------------------------------------------------------
// Kernel A: topk [0,256) + mlp table [256,768)  (unchanged from round 15).
// vals in QUARTER-13 layout: val4T[j<13][n*4+q] covering k = q*13 + j,
// zero-padded to 52.
// ---------------------------------------------------------------------------
__global__ __launch_bounds__(256) void pre_kernel(const float* __restrict__ features,
                                                  const float* __restrict__ sig_w1,
                                                  const float* __restrict__ sig_b1,
                                                  const float* __restrict__ sig_w2,
                                                  int* __restrict__ idxT,
                                                  float* __restrict__ val4T,
                                                  unsigned int* __restrict__ tbl) {
    __shared__ float fsh[N_NEU][KFD + 1];
    __shared__ float sim_sh[N_NEU];

    const int bid = blockIdx.x;

    if (bid < TOPK_BLKS) {
        const int n = bid;
        const int j = threadIdx.x;

        float v[KFD];
        float s = 0.f;
#pragma unroll
        for (int d = 0; d < KFD; ++d) { v[d] = features[j * KFD + d]; s = fmaf(v[d], v[d], s); }
        const float nrm = sqrtf(s);
#pragma unroll
        for (int d = 0; d < KFD; ++d) fsh[j][d] = v[d] / nrm;
        __syncthreads();

        float dot = 0.f;
#pragma unroll
        for (int d = 0; d < KFD; ++d) dot = fmaf(fsh[n][d], fsh[j][d], dot);
        sim_sh[j] = dot;
        __syncthreads();

        if (j < 64) {
            float l0 = sim_sh[j];
            float l1 = sim_sh[j + 64];
            float l2 = sim_sh[j + 128];
            float l3 = sim_sh[j + 192];
            for (int k = 0; k < KN; ++k) {
                float bv = l0; int bi = j;
                if (l1 > bv) { bv = l1; bi = j + 64; }
                if (l2 > bv) { bv = l2; bi = j + 128; }
                if (l3 > bv) { bv = l3; bi = j + 192; }
                for (int off = 32; off > 0; off >>= 1) {
                    float ov = __shfl_xor(bv, off, 64);
                    int   oi = __shfl_xor(bi, off, 64);
                    if (ov > bv || (ov == bv && oi < bi)) { bv = ov; bi = oi; }
                }
                if (j == 0) {
                    const int s_ = k / 13;
                    const int r_ = k - 13 * s_;
                    val4T[r_ * 1024 + n * 4 + s_] = bv;
                    idxT[k * N_NEU + n] = bi;
                }
                if ((bi & 63) == j) {
                    const int q = bi >> 6;
                    if      (q == 0) l0 = -INFINITY;
                    else if (q == 1) l1 = -INFINITY;
                    else if (q == 2) l2 = -INFINITY;
                    else             l3 = -INFINITY;
                }
            }
            if (j == 0) {   // zero-pad k = 50,51 (q=3, r=11,12)
                val4T[11 * 1024 + n * 4 + 3] = 0.f;
                val4T[12 * 1024 + n * 4 + 3] = 0.f;
            }
        }
    } else {
        const int gid = (bid - TOPK_BLKS) * 256 + threadIdx.x;  // k*32+d
        const int k = gid >> 5, d = gid & 31;
        const float s0 = TBL_LO + (float)k / TBL_IDL;
        const float s1 = s0 + 1.0f / TBL_IDL;
        float g0 = 0.f, g1 = 0.f;
#pragma unroll
        for (int j = 0; j < 16; ++j) {
            const float w1 = sig_w1[j], b1 = sig_b1[j], w2 = sig_w2[d * 16 + j];
            const float h0 = fmaf(s0, w1, b1);
            const float h1 = fmaf(s1, w1, b1);
            const float e0 = 0.5f * h0 * (1.0f + erff(h0 * 0.70710678118654752f));
            const float e1 = 0.5f * h1 * (1.0f + erff(h1 * 0.70710678118654752f));
            g0 = fmaf(e0, w2, g0);
            g1 = fmaf(e1, w2, g1);
        }
        g0 *= DT; g1 *= DT;
        tbl[gid] = (unsigned int)f2bf(g0) | ((unsigned int)f2bf(g1 - g0) << 16);
    }
}

// ---------------------------------------------------------------------------
// Per-batch GEMM pass (r15's verified phase-0): 16 waves x 16 u-rows -> cdt_sh.
// ---------------------------------------------------------------------------
__device__ __forceinline__ void gemm_pass(const float* __restrict__ u,
                                          const float* __restrict__ w_in,
                                          const float* __restrict__ b_in,
                                          const float* __restrict__ bias,
                                          const float* __restrict__ sig_b2,
                                          long bB, int t, float* cdt_sh) {
    const int wave = t >> 6;
    const int lane = t & 63;
    const int row  = lane & 15;
    const int kg   = lane >> 4;
    const int wrow = wave * 16;

    bf16x8 bfrag[2][4];
#pragma unroll
    for (int dt_ = 0; dt_ < 2; ++dt_) {
#pragma unroll
        for (int kk = 0; kk < 4; ++kk) {
            const float* wp = w_in + (dt_ * 16 + row) * UINF + kk * 32 + kg * 8;
            const float4 w0 = *reinterpret_cast<const float4*>(wp);
            const float4 w1 = *reinterpret_cast<const float4*>(wp + 4);
            bfrag[dt_][kk] = pack8(w0, w1);
        }
    }

    const float* ub = u + (bB * N_NEU + wrow + row) * UINF + kg * 8;
    float4 L[8];
#pragma unroll
    for (int kk = 0; kk < 4; ++kk) {
        L[kk * 2 + 0] = *reinterpret_cast<const float4*>(ub + kk * 32);
        L[kk * 2 + 1] = *reinterpret_cast<const float4*>(ub + kk * 32 + 4);
    }
    f32x4 a0 = {0.f, 0.f, 0.f, 0.f};
    f32x4 a1 = {0.f, 0.f, 0.f, 0.f};
#pragma unroll
    for (int kk = 0; kk < 4; ++kk) {
        const bf16x8 af = pack8(L[kk * 2], L[kk * 2 + 1]);
        a0 = __builtin_amdgcn_mfma_f32_16x16x32_bf16(af, bfrag[0][kk], a0, 0, 0, 0);
        a1 = __builtin_amdgcn_mfma_f32_16x16x32_bf16(af, bfrag[1][kk], a1, 0, 0, 0);
    }
    const int   d0   = row;
    const int   d1   = 16 + row;
    const float add0 = b_in[d0] + sig_b2[d0];
    const float add1 = b_in[d1] + sig_b2[d1];
#pragma unroll
    for (int r = 0; r < 4; ++r) {
        const int nl = wrow + kg * 4 + r;
        cdt_sh[nl * 36 + d0] = DT * (a0[r] + add0 + bias[nl * D_DIM + d0]);
        cdt_sh[nl * 36 + d1] = DT * (a1[r] + add1 + bias[nl * D_DIM + d1]);
    }
}

// ---------------------------------------------------------------------------
// Kernel B v16: dual-batch SOFTWARE-PIPELINED recurrence.
// Grid 256 x 1024: block owns batches (2blk, 2blk+1); thread (n = t>>2,
// q = t&3) owns 8 dims + 13 gathers for BOTH batches.
// r12-r15 evidence: step time = VALU + LDS + L2 phases added SERIALLY
// (barrier phase-lock). Fix: half-step structure
//   HS1 = { gather+apply B  ||  norm+write A }   (LDS/L2 of B hides under
//   HS2 = { gather+apply A  ||  norm+write B }    VALU of A, and vice versa)
// Single-buffered a_sh is WAR-safe: each write/gather pair is separated by
// a barrier, and A/B halves are disjoint.
// launch_bounds(1024,3) -> VGPR cap ~85 (grid 256 = 1 block/CU regardless,
// so no occupancy cost; avoids r13's catastrophic 32-reg cap).
// ---------------------------------------------------------------------------
__global__ __launch_bounds__(1024, 3) void steps_kernel(const float* __restrict__ u,
                                                        const float* __restrict__ w_in,
                                                        const float* __restrict__ b_in,
                                                        const float* __restrict__ bias,
                                                        const float* __restrict__ sig_b2,
                                                        const int* __restrict__ idxT,
                                                        const float* __restrict__ val4T,
                                                        const unsigned int* __restrict__ tbl,
                                                        float* __restrict__ out) {
    __shared__ float cdt_sh[256 * 36];             // 36864 B (reused per batch)
    __shared__ float a_sh[2 * N_NEU];              // [0..255]=A, [256..511]=B

    const int t  = threadIdx.x;
    const long bA = (long)blockIdx.x * 2;
    const long bB = bA + 1;

    const int n = t >> 2;
    const int q = t & 3;

    // ---- phase 0: GEMM for batch A, extract ccdtA; then batch B ----
    float ccdtA[8], ccdtB[8];
    gemm_pass(u, w_in, b_in, bias, sig_b2, bA, t, cdt_sh);
    __syncthreads();
    {
        const float* cb = &cdt_sh[n * 36 + q * 8];
#pragma unroll
        for (int i = 0; i < 2; ++i) {
            const float4 cv = *reinterpret_cast<const float4*>(cb + i * 4);
            ccdtA[4 * i + 0] = cv.x; ccdtA[4 * i + 1] = cv.y;
            ccdtA[4 * i + 2] = cv.z; ccdtA[4 * i + 3] = cv.w;
        }
    }
    __syncthreads();
    gemm_pass(u, w_in, b_in, bias, sig_b2, bB, t, cdt_sh);
    __syncthreads();
    {
        const float* cb = &cdt_sh[n * 36 + q * 8];
#pragma unroll
        for (int i = 0; i < 2; ++i) {
            const float4 cv = *reinterpret_cast<const float4*>(cb + i * 4);
            ccdtB[4 * i + 0] = cv.x; ccdtB[4 * i + 1] = cv.y;
            ccdtB[4 * i + 2] = cv.z; ccdtB[4 * i + 3] = cv.w;
        }
    }

    // ---- step-invariant per-thread vals + gather pointers ----
    float vvv[13];
#pragma unroll
    for (int j = 0; j < 13; ++j) vvv[j] = val4T[j * 1024 + t];

    const float* gp[13];
#pragma unroll
    for (int j = 0; j < 13; ++j) {
        const int k = q * 13 + j;
        const int ii = (k < KN) ? idxT[k * N_NEU + n] : 0;
        gp[j] = &a_sh[ii];
    }

    float xA[8], xB[8];
#pragma unroll
    for (int d = 0; d < 8; ++d) { xA[d] = 0.f; xB[d] = 0.f; }

    // init: a_B(0) = tanh(sqrt(1e-12)) = 1e-6 (x=0); gathered in first HS1
    if (t < N_NEU) a_sh[N_NEU + t] = 1e-6f;
    __syncthreads();

    const float K1 = 1.0f - DT * GAMMA;   // 0.995

    // GATHER other batch + APPLY it, while NORM+WRITE own batch.
#define HALF_STEP(XG, CCG, GOFF, XN, ANOFF)                                     \
    {                                                                           \
        /* gather (batch G) — issue first so LDS loads fly under the VALU */    \
        float s0 = 0.f, s1 = 0.f;                                               \
        _Pragma("unroll")                                                       \
        for (int j = 0; j < 13; ++j) {                                          \
            const float av = gp[j][(GOFF)];                                     \
            if (j & 1) s1 = fmaf(av, vvv[j], s1);                               \
            else       s0 = fmaf(av, vvv[j], s0);                               \
        }                                                                       \
        /* norm + write (batch N) — independent VALU chain */                   \
        float nh = 0.f;                                                         \
        _Pragma("unroll")                                                       \
        for (int d = 0; d < 8; ++d) nh = fmaf(XN[d], XN[d], nh);                \
        float nfull = nh + __shfl_xor(nh, 1, 64);                               \
        nfull += __shfl_xor(nfull, 2, 64);                                      \
        nfull += 1e-12f;                                                        \
        const float z = sqrtf(nfull);                                           \
        const float an = 1.0f - 2.0f / (__expf(2.0f * z) + 1.0f);               \
        if (q == 0) a_sh[(ANOFF) + n] = an;                                     \
        /* decay (batch G) — independent of gather result */                    \
        _Pragma("unroll")                                                       \
        for (int d = 0; d < 8; ++d) XG[d] = fmaf(K1, XG[d], CCG[d]);            \
        /* reduce syn + table apply (batch G) */                                \
        float syn = s0 + s1;                                                    \
        syn += __shfl_xor(syn, 1, 64);                                          \
        syn += __shfl_xor(syn, 2, 64);                                          \
        const float uu = fmaf(syn, TBL_IDL, -TBL_LO * TBL_IDL);                 \
        int i = (int)uu;                                                        \
        i = (i < 0) ? 0 : (i > TBL_K - 2 ? TBL_K - 2 : i);                      \
        const float tf = uu - (float)i;                                         \
        const uint4* rp = reinterpret_cast<const uint4*>(tbl + (size_t)i * 32 + q * 8); \
        _Pragma("unroll")                                                       \
        for (int c = 0; c < 2; ++c) {                                           \
            const uint4 qv = rp[c];                                             \
            XG[4 * c + 0] = fmaf(tf, bf_hi(qv.x), XG[4 * c + 0] + bf_lo(qv.x)); \
            XG[4 * c + 1] = fmaf(tf, bf_hi(qv.y), XG[4 * c + 1] + bf_lo(qv.y)); \
            XG[4 * c + 2] = fmaf(tf, bf_hi(qv.z), XG[4 * c + 2] + bf_lo(qv.z)); \
            XG[4 * c + 3] = fmaf(tf, bf_hi(qv.w), XG[4 * c + 3] + bf_lo(qv.w)); \
        }                                                                       \
    }

    for (int s = 0; s < NSTEP; ++s) {
        // HS1: gather+apply B  ||  norm+write A
        HALF_STEP(xB, ccdtB, N_NEU, xA, 0);
        __syncthreads();
        // HS2: gather+apply A  ||  norm+write B
        HALF_STEP(xA, ccdtA, 0, xB, N_NEU);
        __syncthreads();
    }
#undef HALF_STEP

    float4* opA = reinterpret_cast<float4*>(out + ((size_t)bA * N_NEU + n) * D_DIM + q * 8);
    float4* opB = reinterpret_cast<float4*>(out + ((size_t)bB * N_NEU + n) * D_DIM + q * 8);
    opA[0] = make_float4(xA[0], xA[1], xA[2], xA[3]);
    opA[1] = make_float4(xA[4], xA[5], xA[6], xA[7]);
    opB[0] = make_float4(xB[0], xB[1], xB[2], xB[3]);
    opB[1] = make_float4(xB[4], xB[5], xB[6], xB[7]);
}

extern "C" void kernel_launch(void* const* d_in, const int* in_sizes, int n_in,
                              void* d_out, int out_size, void* d_ws, size_t ws_size,
                              hipStream_t stream) {
    const float* u        = (const float*)d_in[0];
    const float* features = (const float*)d_in[1];
    const float* bias     = (const float*)d_in[2];
    const float* w_in     = (const float*)d_in[3];
    const float* b_in     = (const float*)d_in[4];
    const float* sig_w1   = (const float*)d_in[5];
    const float* sig_b1   = (const float*)d_in[6];
    const float* sig_w2   = (const float*)d_in[7];
    const float* sig_b2   = (const float*)d_in[8];
    float* out = (float*)d_out;

    char*         ws     = (char*)d_ws;
    int*          idxT   = (int*)ws;                      // 51200 B
    float*        val4T  = (float*)(ws + 51200);          // 53248 B
    unsigned int* tbl    = (unsigned int*)(ws + 104448);  // 512 KiB

    hipLaunchKernelGGL(pre_kernel, dim3(TOPK_BLKS + TBL_BLKS), dim3(256), 0, stream,
                       features, sig_w1, sig_b1, sig_w2, idxT, val4T, tbl);
    hipLaunchKernelGGL(steps_kernel, dim3(B_SZ / 2), dim3(1024), 0, stream,
                       u, w_in, b_in, bias, sig_b2, idxT, val4T, tbl, out);
}

// Round 17
// 99.504 us; speedup vs baseline: 1.1942x; 1.1404x over previous
//
#include <hip/hip_runtime.h>
#include <math.h>

#define N_NEU 256
#define D_DIM 32
#define KFD   16
#define KN    50
#define B_SZ  512
#define UINF  128
#define GAMMA 0.1f
#define DT    0.05f
#define NSTEP 20

// 512-knot piecewise-linear table, Delta = 1/8, range [-8, +56).
// Lerp error ~Delta^2/8 * G'' ~ 1e-6/step (G'' <= ~6e-4); outside the range
// G is affine (gelu saturated/linear) so clamped extrapolation is exact.
#define TBL_K   512
#define TBL_LO  (-8.0f)
#define TBL_IDL 8.0f

#define TOPK_BLKS  N_NEU                 // 256
#define TBL_BLKS   (TBL_K * 32 / 256)    // 64

typedef __attribute__((ext_vector_type(8))) short bf16x8;
typedef __attribute__((ext_vector_type(4))) float f32x4;

__device__ __forceinline__ unsigned short f2bf(float f) {
    unsigned u = __float_as_uint(f);
    u += 0x7FFFu + ((u >> 16) & 1u);     // round-to-nearest-even
    return (unsigned short)(u >> 16);
}
__device__ __forceinline__ float bf_lo(unsigned q) { return __uint_as_float(q << 16); }
__device__ __forceinline__ float bf_hi(unsigned q) { return __uint_as_float(q & 0xFFFF0000u); }

__device__ __forceinline__ bf16x8 pack8(float4 a0, float4 a1) {
    bf16x8 f;
    f[0] = (short)f2bf(a0.x); f[1] = (short)f2bf(a0.y);
    f[2] = (short)f2bf(a0.z); f[3] = (short)f2bf(a0.w);
    f[4] = (short)f2bf(a1.x); f[5] = (short)f2bf(a1.y);
    f[6] = (short)f2bf(a1.z); f[7] = (short)f2bf(a1.w);
    return f;
}

// ---------------------------------------------------------------------------
// Kernel A: topk [0,256) + mlp table [256,320).
// vals ZERO-PADDED to 56 (4 subthreads x 14 k's) in pair layout:
//   float2 [jj][n*4+s], jj<7, covering k = s*14 + 2*jj + p.
// ---------------------------------------------------------------------------
__global__ __launch_bounds__(256) void pre_kernel(const float* __restrict__ features,
                                                  const float* __restrict__ sig_w1,
                                                  const float* __restrict__ sig_b1,
                                                  const float* __restrict__ sig_w2,
                                                  int* __restrict__ idxT,
                                                  float* __restrict__ vals2T,
                                                  unsigned int* __restrict__ tbl) {
    __shared__ float fsh[N_NEU][KFD + 1];
    __shared__ float sim_sh[N_NEU];

    const int bid = blockIdx.x;

    if (bid < TOPK_BLKS) {
        // ---- topk ----
        const int n = bid;
        const int j = threadIdx.x;

        float v[KFD];
        float s = 0.f;
#pragma unroll
        for (int d = 0; d < KFD; ++d) { v[d] = features[j * KFD + d]; s = fmaf(v[d], v[d], s); }
        const float nrm = sqrtf(s);
#pragma unroll
        for (int d = 0; d < KFD; ++d) fsh[j][d] = v[d] / nrm;
        __syncthreads();

        float dot = 0.f;
#pragma unroll
        for (int d = 0; d < KFD; ++d) dot = fmaf(fsh[n][d], fsh[j][d], dot);
        sim_sh[j] = dot;
        __syncthreads();

        if (j < 64) {
            float l0 = sim_sh[j];
            float l1 = sim_sh[j + 64];
            float l2 = sim_sh[j + 128];
            float l3 = sim_sh[j + 192];
            for (int k = 0; k < KN; ++k) {
                float bv = l0; int bi = j;
                if (l1 > bv) { bv = l1; bi = j + 64; }
                if (l2 > bv) { bv = l2; bi = j + 128; }
                if (l3 > bv) { bv = l3; bi = j + 192; }
                for (int off = 32; off > 0; off >>= 1) {
                    float ov = __shfl_xor(bv, off, 64);
                    int   oi = __shfl_xor(bi, off, 64);
                    if (ov > bv || (ov == bv && oi < bi)) { bv = ov; bi = oi; }
                }
                if (j == 0) {
                    const int s_ = k / 14;
                    const int r_ = k - 14 * s_;
                    vals2T[((r_ >> 1) * 1024 + n * 4 + s_) * 2 + (r_ & 1)] = bv;
                    idxT[k * N_NEU + n] = bi;
                }
                if ((bi & 63) == j) {
                    const int q = bi >> 6;
                    if      (q == 0) l0 = -INFINITY;
                    else if (q == 1) l1 = -INFINITY;
                    else if (q == 2) l2 = -INFINITY;
                    else             l3 = -INFINITY;
                }
            }
            if (j == 0) {   // zero-pad k = 50..55 (subthread 3, r = 8..13)
#pragma unroll
                for (int k = 50; k < 56; ++k) {
                    const int r_ = k - 42;
                    vals2T[((r_ >> 1) * 1024 + n * 4 + 3) * 2 + (r_ & 1)] = 0.f;
                }
            }
        }
    } else {
        // ---- mlp table (512 knots) ----
        const int gid = (bid - TOPK_BLKS) * 256 + threadIdx.x;  // k*32+d
        const int k = gid >> 5, d = gid & 31;
        const float s0 = TBL_LO + (float)k / TBL_IDL;
        const float s1 = s0 + 1.0f / TBL_IDL;
        float g0 = 0.f, g1 = 0.f;
#pragma unroll
        for (int j = 0; j < 16; ++j) {
            const float w1 = sig_w1[j], b1 = sig_b1[j], w2 = sig_w2[d * 16 + j];
            const float h0 = fmaf(s0, w1, b1);
            const float h1 = fmaf(s1, w1, b1);
            const float e0 = 0.5f * h0 * (1.0f + erff(h0 * 0.70710678118654752f));
            const float e1 = 0.5f * h1 * (1.0f + erff(h1 * 0.70710678118654752f));
            g0 = fmaf(e0, w2, g0);
            g1 = fmaf(e1, w2, g1);
        }
        g0 *= DT; g1 *= DT;
        tbl[gid] = (unsigned int)f2bf(g0) | ((unsigned int)f2bf(g1 - g0) << 16);
    }
}

// ---------------------------------------------------------------------------
// Kernel B: fused uproj-GEMM + 20-step recurrence (r14 structure = best
// measured step engine: packed 2-batch bf16 gather, one barrier/step).
// NEW vs r14: the sigma-MLP table lives in LDS (tbl_sh, stride 36 u32:
// rows 16B-aligned for ds_read_b128, start banks spread 8-way -> 2-way
// conflict = free). Removes the per-step L2 table load (~200-400 cyc in the
// 20x serial convoy) and ~160 MB of L2 traffic.
// LDS: cdt_sh 73728 + a_sh 2048 + tbl_sh 73728 = 149504 <= 160K (1 blk/CU).
// launch_bounds(1024,4) -> VGPR cap 64 = natural allocation (r14: 56, no
// spill; r13's N=8 -> 32-reg cap catastrophically spilled).
// ---------------------------------------------------------------------------
__global__ __launch_bounds__(1024, 4) void steps_kernel(const float* __restrict__ u,
                                                        const float* __restrict__ w_in,
                                                        const float* __restrict__ b_in,
                                                        const float* __restrict__ bias,
                                                        const float* __restrict__ sig_b2,
                                                        const int* __restrict__ idxT,
                                                        const float* __restrict__ vals2T,
                                                        const unsigned int* __restrict__ tbl,
                                                        float* __restrict__ out) {
    __shared__ float cdt_sh[2 * 256 * 36];         // 73728 B, row stride 36
    __shared__ unsigned int a_sh[2 * N_NEU];       // 2048 B, packed 2-batch bf16
    __shared__ unsigned int tbl_sh[TBL_K * 36];    // 73728 B, row stride 36

    const int t = threadIdx.x;

    // ---- stage table -> LDS (coalesced; overlaps GEMM's global loads) ----
#pragma unroll
    for (int i = t; i < TBL_K * 32; i += 1024)
        tbl_sh[(i >> 5) * 36 + (i & 31)] = tbl[i];

    // ---- phase 0: per-wave 32-row GEMM (w_in fragments straight from L2) ----
    {
        const int wave = t >> 6;
        const int lane = t & 63;
        const int row  = lane & 15;
        const int kg   = lane >> 4;
        const int bb0  = wave >> 3;                    // which batch of the pair
        const int wrow = (wave & 7) * 32;              // first neuron row of wave
        const long bB  = (long)blockIdx.x * 2 + bb0;

        bf16x8 bfrag[2][4];
#pragma unroll
        for (int dt_ = 0; dt_ < 2; ++dt_) {
#pragma unroll
            for (int kk = 0; kk < 4; ++kk) {
                const float* wp = w_in + (dt_ * 16 + row) * UINF + kk * 32 + kg * 8;
                const float4 w0 = *reinterpret_cast<const float4*>(wp);
                const float4 w1 = *reinterpret_cast<const float4*>(wp + 4);
                bfrag[dt_][kk] = pack8(w0, w1);
            }
        }

#pragma unroll
        for (int t4 = 0; t4 < 2; ++t4) {
            const float* ub = u + (bB * N_NEU + wrow + t4 * 16 + row) * UINF + kg * 8;
            float4 L[8];
#pragma unroll
            for (int kk = 0; kk < 4; ++kk) {
                L[kk * 2 + 0] = *reinterpret_cast<const float4*>(ub + kk * 32);
                L[kk * 2 + 1] = *reinterpret_cast<const float4*>(ub + kk * 32 + 4);
            }
            f32x4 a0 = {0.f, 0.f, 0.f, 0.f};
            f32x4 a1 = {0.f, 0.f, 0.f, 0.f};
#pragma unroll
            for (int kk = 0; kk < 4; ++kk) {
                const bf16x8 af = pack8(L[kk * 2], L[kk * 2 + 1]);
                a0 = __builtin_amdgcn_mfma_f32_16x16x32_bf16(af, bfrag[0][kk], a0, 0, 0, 0);
                a1 = __builtin_amdgcn_mfma_f32_16x16x32_bf16(af, bfrag[1][kk], a1, 0, 0, 0);
            }
            const int   d0   = row;
            const int   d1   = 16 + row;
            const float add0 = b_in[d0] + sig_b2[d0];
            const float add1 = b_in[d1] + sig_b2[d1];
#pragma unroll
            for (int r = 0; r < 4; ++r) {
                const int nl = wrow + t4 * 16 + kg * 4 + r;
                cdt_sh[bb0 * 9216 + nl * 36 + d0] = DT * (a0[r] + add0 + bias[nl * D_DIM + d0]);
                cdt_sh[bb0 * 9216 + nl * 36 + d1] = DT * (a1[r] + add1 + bias[nl * D_DIM + d1]);
            }
        }
    }
    __syncthreads();

    // ---- redistribute to per-thread ccdt regs ----
    const int n  = t >> 2;
    const int s  = t & 3;
    const int bb = s >> 1;
    const int h  = s & 1;
    const int b  = blockIdx.x * 2 + bb;

    float ccdt[16];
    {
        const float* cbase = &cdt_sh[bb * 9216 + n * 36 + h * 16];
#pragma unroll
        for (int i = 0; i < 4; ++i) {
            const float4 cv = *reinterpret_cast<const float4*>(cbase + i * 4);
            ccdt[4 * i + 0] = cv.x; ccdt[4 * i + 1] = cv.y;
            ccdt[4 * i + 2] = cv.z; ccdt[4 * i + 3] = cv.w;
        }
    }

    // ---- step-invariant per-thread vals + gather pointers ----
    const float2* v2g = reinterpret_cast<const float2*>(vals2T);
    float2 vv[7];
#pragma unroll
    for (int jj = 0; jj < 7; ++jj) vv[jj] = v2g[jj * 1024 + t];

    const unsigned int* gp[14];
#pragma unroll
    for (int j = 0; j < 14; ++j) {
        const int k = s * 14 + j;
        const int ii = (k < KN) ? idxT[k * N_NEU + n] : 0;
        gp[j] = &a_sh[ii];
    }

    float x[16];
#pragma unroll
    for (int d = 0; d < 16; ++d) x[d] = 0.f;

    const float K1 = 1.0f - DT * GAMMA;   // 0.995

#define STEP_BODY(BUF)                                                          \
    {                                                                           \
        float nh0 = 0.f, nh1 = 0.f;                                             \
        _Pragma("unroll")                                                       \
        for (int d = 0; d < 16; d += 2) {                                       \
            nh0 = fmaf(x[d], x[d], nh0);                                        \
            nh1 = fmaf(x[d + 1], x[d + 1], nh1);                                \
        }                                                                       \
        const float nh = nh0 + nh1;                                             \
        const float nfull = nh + __shfl_xor(nh, 1, 64) + 1e-12f;                \
        const float z = sqrtf(nfull);                                           \
        const float a = 1.0f - 2.0f / (__expf(2.0f * z) + 1.0f);                \
        const float ao = __shfl_xor(a, 2, 64);                                  \
        if (s == 0) a_sh[(BUF) * N_NEU + n] = (unsigned int)f2bf(a) | ((unsigned int)f2bf(ao) << 16); \
        _Pragma("unroll")                                                       \
        for (int d = 0; d < 16; ++d) x[d] = fmaf(K1, x[d], ccdt[d]);            \
        __syncthreads();                                                        \
        float sA0 = 0.f, sA1 = 0.f, sB0 = 0.f, sB1 = 0.f;                       \
        _Pragma("unroll")                                                       \
        for (int jj = 0; jj < 7; ++jj) {                                        \
            const unsigned int p0 = gp[2 * jj][(BUF) * N_NEU];                  \
            const unsigned int p1 = gp[2 * jj + 1][(BUF) * N_NEU];              \
            sA0 = fmaf(bf_lo(p0), vv[jj].x, sA0);                               \
            sB0 = fmaf(bf_hi(p0), vv[jj].x, sB0);                               \
            sA1 = fmaf(bf_lo(p1), vv[jj].y, sA1);                               \
            sB1 = fmaf(bf_hi(p1), vv[jj].y, sB1);                               \
        }                                                                       \
        float sA = sA0 + sA1;                                                   \
        float sB = sB0 + sB1;                                                   \
        sA += __shfl_xor(sA, 1, 64); sA += __shfl_xor(sA, 2, 64);               \
        sB += __shfl_xor(sB, 1, 64); sB += __shfl_xor(sB, 2, 64);               \
        const float syn = bb ? sB : sA;                                         \
        const float uu = fmaf(syn, TBL_IDL, -TBL_LO * TBL_IDL);                 \
        int i = (int)uu;                                                        \
        i = (i < 0) ? 0 : (i > TBL_K - 2 ? TBL_K - 2 : i);                      \
        const float tf = uu - (float)i;                                         \
        const uint4* rp = reinterpret_cast<const uint4*>(&tbl_sh[i * 36 + h * 16]); \
        _Pragma("unroll")                                                       \
        for (int c = 0; c < 2; ++c) {                                           \
            const uint4 q = rp[c];                                              \
            x[8 * c + 0] = fmaf(tf, bf_hi(q.x), x[8 * c + 0] + bf_lo(q.x));     \
            x[8 * c + 1] = fmaf(tf, bf_hi(q.y), x[8 * c + 1] + bf_lo(q.y));     \
            x[8 * c + 2] = fmaf(tf, bf_hi(q.z), x[8 * c + 2] + bf_lo(q.z));     \
            x[8 * c + 3] = fmaf(tf, bf_hi(q.w), x[8 * c + 3] + bf_lo(q.w));     \
            const uint4 q2 = rp[2 * c + 1];                                     \
            x[8 * c + 4] = fmaf(tf, bf_hi(q2.x), x[8 * c + 4] + bf_lo(q2.x));   \
            x[8 * c + 5] = fmaf(tf, bf_hi(q2.y), x[8 * c + 5] + bf_lo(q2.y));   \
            x[8 * c + 6] = fmaf(tf, bf_hi(q2.z), x[8 * c + 6] + bf_lo(q2.z));   \
            x[8 * c + 7] = fmaf(tf, bf_hi(q2.w), x[8 * c + 7] + bf_lo(q2.w));   \
        }                                                                       \
    }

    // NOTE on the table-apply indexing above: rp[c] walks uint4s 0..3 of this
    // thread's 16-dim half (h*16 offset already applied); the pairing
    // (rp[0],rp[1]) -> x[0..7], (rp[2],rp[3]) -> x[8..15] must be sequential.
    // Rewritten plainly to avoid confusion:
#undef STEP_BODY
#define STEP_BODY(BUF)                                                          \
    {                                                                           \
        float nh0 = 0.f, nh1 = 0.f;                                             \
        _Pragma("unroll")                                                       \
        for (int d = 0; d < 16; d += 2) {                                       \
            nh0 = fmaf(x[d], x[d], nh0);                                        \
            nh1 = fmaf(x[d + 1], x[d + 1], nh1);                                \
        }                                                                       \
        const float nh = nh0 + nh1;                                             \
        const float nfull = nh + __shfl_xor(nh, 1, 64) + 1e-12f;                \
        const float z = sqrtf(nfull);                                           \
        const float a = 1.0f - 2.0f / (__expf(2.0f * z) + 1.0f);                \
        const float ao = __shfl_xor(a, 2, 64);                                  \
        if (s == 0) a_sh[(BUF) * N_NEU + n] = (unsigned int)f2bf(a) | ((unsigned int)f2bf(ao) << 16); \
        _Pragma("unroll")                                                       \
        for (int d = 0; d < 16; ++d) x[d] = fmaf(K1, x[d], ccdt[d]);            \
        __syncthreads();                                                        \
        float sA0 = 0.f, sA1 = 0.f, sB0 = 0.f, sB1 = 0.f;                       \
        _Pragma("unroll")                                                       \
        for (int jj = 0; jj < 7; ++jj) {                                        \
            const unsigned int p0 = gp[2 * jj][(BUF) * N_NEU];                  \
            const unsigned int p1 = gp[2 * jj + 1][(BUF) * N_NEU];              \
            sA0 = fmaf(bf_lo(p0), vv[jj].x, sA0);                               \
            sB0 = fmaf(bf_hi(p0), vv[jj].x, sB0);                               \
            sA1 = fmaf(bf_lo(p1), vv[jj].y, sA1);                               \
            sB1 = fmaf(bf_hi(p1), vv[jj].y, sB1);                               \
        }                                                                       \
        float sA = sA0 + sA1;                                                   \
        float sB = sB0 + sB1;                                                   \
        sA += __shfl_xor(sA, 1, 64); sA += __shfl_xor(sA, 2, 64);               \
        sB += __shfl_xor(sB, 1, 64); sB += __shfl_xor(sB, 2, 64);               \
        const float syn = bb ? sB : sA;                                         \
        const float uu = fmaf(syn, TBL_IDL, -TBL_LO * TBL_IDL);                 \
        int i = (int)uu;                                                        \
        i = (i < 0) ? 0 : (i > TBL_K - 2 ? TBL_K - 2 : i);                      \
        const float tf = uu - (float)i;                                         \
        const uint4* rp = reinterpret_cast<const uint4*>(&tbl_sh[i * 36 + h * 16]); \
        _Pragma("unroll")                                                       \
        for (int c = 0; c < 4; ++c) {                                           \
            const uint4 q = rp[c];                                              \
            x[4 * c + 0] = fmaf(tf, bf_hi(q.x), x[4 * c + 0] + bf_lo(q.x));     \
            x[4 * c + 1] = fmaf(tf, bf_hi(q.y), x[4 * c + 1] + bf_lo(q.y));     \
            x[4 * c + 2] = fmaf(tf, bf_hi(q.z), x[4 * c + 2] + bf_lo(q.z));     \
            x[4 * c + 3] = fmaf(tf, bf_hi(q.w), x[4 * c + 3] + bf_lo(q.w));     \
        }                                                                       \
    }

    for (int it = 0; it < NSTEP / 2; ++it) {
        STEP_BODY(0);
        STEP_BODY(1);
    }
#undef STEP_BODY

    float4* op4 = reinterpret_cast<float4*>(out + ((size_t)b * N_NEU + n) * D_DIM + h * 16);
#pragma unroll
    for (int i = 0; i < 4; ++i)
        op4[i] = make_float4(x[4 * i + 0], x[4 * i + 1], x[4 * i + 2], x[4 * i + 3]);
}

extern "C" void kernel_launch(void* const* d_in, const int* in_sizes, int n_in,
                              void* d_out, int out_size, void* d_ws, size_t ws_size,
                              hipStream_t stream) {
    const float* u        = (const float*)d_in[0];
    const float* features = (const float*)d_in[1];
    const float* bias     = (const float*)d_in[2];
    const float* w_in     = (const float*)d_in[3];
    const float* b_in     = (const float*)d_in[4];
    const float* sig_w1   = (const float*)d_in[5];
    const float* sig_b1   = (const float*)d_in[6];
    const float* sig_w2   = (const float*)d_in[7];
    const float* sig_b2   = (const float*)d_in[8];
    float* out = (float*)d_out;

    char*         ws     = (char*)d_ws;
    int*          idxT   = (int*)ws;                      // 51200 B
    float*        vals2T = (float*)(ws + 51200);          // 57344 B
    unsigned int* tbl    = (unsigned int*)(ws + 108544);  // 512*32*4 = 65536 B

    hipLaunchKernelGGL(pre_kernel, dim3(TOPK_BLKS + TBL_BLKS), dim3(256), 0, stream,
                       features, sig_w1, sig_b1, sig_w2, idxT, vals2T, tbl);
    hipLaunchKernelGGL(steps_kernel, dim3(B_SZ / 2), dim3(1024), 0, stream,
                       u, w_in, b_in, bias, sig_b2, idxT, vals2T, tbl, out);
}

// Round 18
// 97.390 us; speedup vs baseline: 1.2201x; 1.0217x over previous
//
#include <hip/hip_runtime.h>
#include <math.h>

#define N_NEU 256
#define D_DIM 32
#define KFD   16
#define KN    50
#define B_SZ  512
#define UINF  128
#define GAMMA 0.1f
#define DT    0.05f
#define NSTEP 20

// 512-knot piecewise-linear table, Delta = 1/8, range [-8, +56).
#define TBL_K   512
#define TBL_LO  (-8.0f)
#define TBL_IDL 8.0f

#define TOPK_BLKS  N_NEU                 // 256
#define TBL_BLKS   (TBL_K * 32 / 256)    // 64

typedef __attribute__((ext_vector_type(8))) short bf16x8;
typedef __attribute__((ext_vector_type(4))) float f32x4;

__device__ __forceinline__ unsigned short f2bf(float f) {
    unsigned u = __float_as_uint(f);
    u += 0x7FFFu + ((u >> 16) & 1u);     // round-to-nearest-even
    return (unsigned short)(u >> 16);
}
__device__ __forceinline__ float bf_lo(unsigned q) { return __uint_as_float(q << 16); }
__device__ __forceinline__ float bf_hi(unsigned q) { return __uint_as_float(q & 0xFFFF0000u); }

__device__ __forceinline__ bf16x8 pack8(float4 a0, float4 a1) {
    bf16x8 f;
    f[0] = (short)f2bf(a0.x); f[1] = (short)f2bf(a0.y);
    f[2] = (short)f2bf(a0.z); f[3] = (short)f2bf(a0.w);
    f[4] = (short)f2bf(a1.x); f[5] = (short)f2bf(a1.y);
    f[6] = (short)f2bf(a1.z); f[7] = (short)f2bf(a1.w);
    return f;
}

// ---------------------------------------------------------------------------
// Kernel A: topk [0,256) + mlp table [256,320).
// Outputs plain layouts: idxT[k*256+n], valsP[k*256+n] (steps builds its own
// dense-W from them; no per-thread vals layout needed anymore).
// ---------------------------------------------------------------------------
__global__ __launch_bounds__(256) void pre_kernel(const float* __restrict__ features,
                                                  const float* __restrict__ sig_w1,
                                                  const float* __restrict__ sig_b1,
                                                  const float* __restrict__ sig_w2,
                                                  int* __restrict__ idxT,
                                                  float* __restrict__ valsP,
                                                  unsigned int* __restrict__ tbl) {
    __shared__ float fsh[N_NEU][KFD + 1];
    __shared__ float sim_sh[N_NEU];

    const int bid = blockIdx.x;

    if (bid < TOPK_BLKS) {
        // ---- topk ----
        const int n = bid;
        const int j = threadIdx.x;

        float v[KFD];
        float s = 0.f;
#pragma unroll
        for (int d = 0; d < KFD; ++d) { v[d] = features[j * KFD + d]; s = fmaf(v[d], v[d], s); }
        const float nrm = sqrtf(s);
#pragma unroll
        for (int d = 0; d < KFD; ++d) fsh[j][d] = v[d] / nrm;
        __syncthreads();

        float dot = 0.f;
#pragma unroll
        for (int d = 0; d < KFD; ++d) dot = fmaf(fsh[n][d], fsh[j][d], dot);
        sim_sh[j] = dot;
        __syncthreads();

        if (j < 64) {
            float l0 = sim_sh[j];
            float l1 = sim_sh[j + 64];
            float l2 = sim_sh[j + 128];
            float l3 = sim_sh[j + 192];
            for (int k = 0; k < KN; ++k) {
                float bv = l0; int bi = j;
                if (l1 > bv) { bv = l1; bi = j + 64; }
                if (l2 > bv) { bv = l2; bi = j + 128; }
                if (l3 > bv) { bv = l3; bi = j + 192; }
                for (int off = 32; off > 0; off >>= 1) {
                    float ov = __shfl_xor(bv, off, 64);
                    int   oi = __shfl_xor(bi, off, 64);
                    if (ov > bv || (ov == bv && oi < bi)) { bv = ov; bi = oi; }
                }
                if (j == 0) {
                    valsP[k * N_NEU + n] = bv;
                    idxT[k * N_NEU + n] = bi;
                }
                if ((bi & 63) == j) {
                    const int q = bi >> 6;
                    if      (q == 0) l0 = -INFINITY;
                    else if (q == 1) l1 = -INFINITY;
                    else if (q == 2) l2 = -INFINITY;
                    else             l3 = -INFINITY;
                }
            }
        }
    } else {
        // ---- mlp table (512 knots, plain [k][32] u32 layout) ----
        const int gid = (bid - TOPK_BLKS) * 256 + threadIdx.x;  // k*32+d
        const int k = gid >> 5, d = gid & 31;
        const float s0 = TBL_LO + (float)k / TBL_IDL;
        const float s1 = s0 + 1.0f / TBL_IDL;
        float g0 = 0.f, g1 = 0.f;
#pragma unroll
        for (int j = 0; j < 16; ++j) {
            const float w1 = sig_w1[j], b1 = sig_b1[j], w2 = sig_w2[d * 16 + j];
            const float h0 = fmaf(s0, w1, b1);
            const float h1 = fmaf(s1, w1, b1);
            const float e0 = 0.5f * h0 * (1.0f + erff(h0 * 0.70710678118654752f));
            const float e1 = 0.5f * h1 * (1.0f + erff(h1 * 0.70710678118654752f));
            g0 = fmaf(e0, w2, g0);
            g1 = fmaf(e1, w2, g1);
        }
        g0 *= DT; g1 *= DT;
        tbl[gid] = (unsigned int)f2bf(g0) | ((unsigned int)f2bf(g1 - g0) << 16);
    }
}

// ---------------------------------------------------------------------------
// Kernel B v18: fused uproj-GEMM + 20-step recurrence with MFMA-based syn.
// The random 50-neighbor gather (r14's ~1100 conflict-cyc/CU-step — intrinsic
// to 64 random addresses over 32 banks) is replaced by a dense matvec:
//   syn[2 x 256] = A[2 x 256] @ W^T,  W[n][m] = vals at m=idx (19.5% dense,
// batch-independent, step-invariant). W is built ONCE per block in LDS
// (128 KB, reusing the cdt_sh region after ccdt extraction) in MFMA B-frag
// layout. Per step per wave: 8 conflict-free A-frag b128 reads + 8 B-frag
// b128 reads + 8 mfma_16x16x32_bf16; wave w's threads ARE n-tile w, so syn
// returns via 2 intra-wave shfl — still ONE barrier per step.
// Fragment conventions copied from the (test-proven) uproj GEMM; C-row =
// batch per the m89 layout (rows 0,1 = acc[0],acc[1] of lanes 0..15).
// LDS: max(cdt 73.7K, W 128K) + a 2K = 133.1K, 1 block/CU (grid 256).
// ---------------------------------------------------------------------------
__global__ __launch_bounds__(1024, 4) void steps_kernel(const float* __restrict__ u,
                                                        const float* __restrict__ w_in,
                                                        const float* __restrict__ b_in,
                                                        const float* __restrict__ bias,
                                                        const float* __restrict__ sig_b2,
                                                        const int* __restrict__ idxT,
                                                        const float* __restrict__ valsP,
                                                        const unsigned int* __restrict__ tbl,
                                                        float* __restrict__ out) {
    __shared__ uint4 SMEM4[131072 / 16 + 2048 / 16];     // 133120 B total
    float*          cdt_sh = (float*)SMEM4;              // [2*256*36] during GEMM
    unsigned short* W      = (unsigned short*)SMEM4;     // [131072 B] after GEMM
    unsigned short* a_u16  = (unsigned short*)((char*)SMEM4 + 131072); // [2][2][256]

    const int t = threadIdx.x;

    // ---- phase 0: per-wave 32-row GEMM (r17 structure, verified) ----
    {
        const int wave = t >> 6;
        const int lane = t & 63;
        const int row  = lane & 15;
        const int kg   = lane >> 4;
        const int bb0  = wave >> 3;
        const int wrow = (wave & 7) * 32;
        const long bB  = (long)blockIdx.x * 2 + bb0;

        bf16x8 bfrag[2][4];
#pragma unroll
        for (int dt_ = 0; dt_ < 2; ++dt_) {
#pragma unroll
            for (int kk = 0; kk < 4; ++kk) {
                const float* wp = w_in + (dt_ * 16 + row) * UINF + kk * 32 + kg * 8;
                const float4 w0 = *reinterpret_cast<const float4*>(wp);
                const float4 w1 = *reinterpret_cast<const float4*>(wp + 4);
                bfrag[dt_][kk] = pack8(w0, w1);
            }
        }

#pragma unroll
        for (int t4 = 0; t4 < 2; ++t4) {
            const float* ub = u + (bB * N_NEU + wrow + t4 * 16 + row) * UINF + kg * 8;
            float4 L[8];
#pragma unroll
            for (int kk = 0; kk < 4; ++kk) {
                L[kk * 2 + 0] = *reinterpret_cast<const float4*>(ub + kk * 32);
                L[kk * 2 + 1] = *reinterpret_cast<const float4*>(ub + kk * 32 + 4);
            }
            f32x4 a0 = {0.f, 0.f, 0.f, 0.f};
            f32x4 a1 = {0.f, 0.f, 0.f, 0.f};
#pragma unroll
            for (int kk = 0; kk < 4; ++kk) {
                const bf16x8 af = pack8(L[kk * 2], L[kk * 2 + 1]);
                a0 = __builtin_amdgcn_mfma_f32_16x16x32_bf16(af, bfrag[0][kk], a0, 0, 0, 0);
                a1 = __builtin_amdgcn_mfma_f32_16x16x32_bf16(af, bfrag[1][kk], a1, 0, 0, 0);
            }
            const int   d0   = row;
            const int   d1   = 16 + row;
            const float add0 = b_in[d0] + sig_b2[d0];
            const float add1 = b_in[d1] + sig_b2[d1];
#pragma unroll
            for (int r = 0; r < 4; ++r) {
                const int nl = wrow + t4 * 16 + kg * 4 + r;
                cdt_sh[bb0 * 9216 + nl * 36 + d0] = DT * (a0[r] + add0 + bias[nl * D_DIM + d0]);
                cdt_sh[bb0 * 9216 + nl * 36 + d1] = DT * (a1[r] + add1 + bias[nl * D_DIM + d1]);
            }
        }
    }
    __syncthreads();

    // ---- thread mapping: n = t>>2 (wave w = n>>4 owns n-tile w), s = t&3 ----
    const int n  = t >> 2;
    const int s  = t & 3;
    const int bb = s >> 1;
    const int h  = s & 1;
    const int b  = blockIdx.x * 2 + bb;
    const int lane = t & 63;
    const int wv   = t >> 6;

    float ccdt[16];
    {
        const float* cbase = &cdt_sh[bb * 9216 + n * 36 + h * 16];
#pragma unroll
        for (int i = 0; i < 4; ++i) {
            const float4 cv = *reinterpret_cast<const float4*>(cbase + i * 4);
            ccdt[4 * i + 0] = cv.x; ccdt[4 * i + 1] = cv.y;
            ccdt[4 * i + 2] = cv.z; ccdt[4 * i + 3] = cv.w;
        }
    }
    __syncthreads();   // all ccdt extracted; cdt_sh region now reusable for W

    // ---- build W in B-frag layout: zero then scatter ----
    {
        const uint4 z = {0u, 0u, 0u, 0u};
#pragma unroll
        for (int i = 0; i < 8; ++i) SMEM4[t + i * 1024] = z;   // 131072 B
    }
    __syncthreads();
#pragma unroll
    for (int j = 0; j < 13; ++j) {
        const int k = s * 13 + j;
        if (k < KN) {
            const int   ii  = idxT[k * N_NEU + n];
            const float val = valsP[k * N_NEU + n];
            const int w_  = n >> 4, ln = n & 15;
            const int kk  = ii >> 5, kg = (ii >> 3) & 3, e = ii & 7;
            W[((w_ * 8 + kk) * 64 + kg * 16 + ln) * 8 + e] = f2bf(val);
        }
    }
    __syncthreads();

    float x[16];
#pragma unroll
    for (int d = 0; d < 16; ++d) x[d] = 0.f;

    const float K1 = 1.0f - DT * GAMMA;   // 0.995
    const int rowc = (lane & 15) & 1;     // clamp A-row to {0,1}; rows 2-15 dup
    const int kgl  = lane >> 4;

#define STEP_BODY(BUF)                                                          \
    {                                                                           \
        float nh0 = 0.f, nh1 = 0.f;                                             \
        _Pragma("unroll")                                                       \
        for (int d = 0; d < 16; d += 2) {                                       \
            nh0 = fmaf(x[d], x[d], nh0);                                        \
            nh1 = fmaf(x[d + 1], x[d + 1], nh1);                                \
        }                                                                       \
        const float nh = nh0 + nh1;                                             \
        const float nfull = nh + __shfl_xor(nh, 1, 64) + 1e-12f;                \
        const float z = sqrtf(nfull);                                           \
        const float a = 1.0f - 2.0f / (__expf(2.0f * z) + 1.0f);                \
        if (h == 0) a_u16[((BUF) * 2 + bb) * N_NEU + n] = f2bf(a);              \
        _Pragma("unroll")                                                       \
        for (int d = 0; d < 16; ++d) x[d] = fmaf(K1, x[d], ccdt[d]);            \
        __syncthreads();                                                        \
        /* dense syn via MFMA: wave wv computes its own n-tile */               \
        f32x4 acc = {0.f, 0.f, 0.f, 0.f};                                       \
        _Pragma("unroll")                                                       \
        for (int kk = 0; kk < 8; ++kk) {                                        \
            const bf16x8 af = *reinterpret_cast<const bf16x8*>(                 \
                &a_u16[((BUF) * 2 + rowc) * N_NEU + kk * 32 + kgl * 8]);        \
            const bf16x8 bf = *reinterpret_cast<const bf16x8*>(                 \
                &W[((wv * 8 + kk) * 64 + lane) * 8]);                           \
            acc = __builtin_amdgcn_mfma_f32_16x16x32_bf16(af, bf, acc, 0, 0, 0);\
        }                                                                       \
        const float sy0 = __shfl(acc[0], lane >> 2, 64);                        \
        const float sy1 = __shfl(acc[1], lane >> 2, 64);                        \
        const float syn = bb ? sy1 : sy0;                                       \
        const float uu = fmaf(syn, TBL_IDL, -TBL_LO * TBL_IDL);                 \
        int i = (int)uu;                                                        \
        i = (i < 0) ? 0 : (i > TBL_K - 2 ? TBL_K - 2 : i);                      \
        const float tf = uu - (float)i;                                         \
        const uint4* rp = reinterpret_cast<const uint4*>(tbl + (size_t)i * 32 + h * 16); \
        _Pragma("unroll")                                                       \
        for (int c = 0; c < 4; ++c) {                                           \
            const uint4 qv = rp[c];                                             \
            x[4 * c + 0] = fmaf(tf, bf_hi(qv.x), x[4 * c + 0] + bf_lo(qv.x));   \
            x[4 * c + 1] = fmaf(tf, bf_hi(qv.y), x[4 * c + 1] + bf_lo(qv.y));   \
            x[4 * c + 2] = fmaf(tf, bf_hi(qv.z), x[4 * c + 2] + bf_lo(qv.z));   \
            x[4 * c + 3] = fmaf(tf, bf_hi(qv.w), x[4 * c + 3] + bf_lo(qv.w));   \
        }                                                                       \
    }

    for (int it = 0; it < NSTEP / 2; ++it) {
        STEP_BODY(0);
        STEP_BODY(1);
    }
#undef STEP_BODY

    float4* op4 = reinterpret_cast<float4*>(out + ((size_t)b * N_NEU + n) * D_DIM + h * 16);
#pragma unroll
    for (int i = 0; i < 4; ++i)
        op4[i] = make_float4(x[4 * i + 0], x[4 * i + 1], x[4 * i + 2], x[4 * i + 3]);
}

extern "C" void kernel_launch(void* const* d_in, const int* in_sizes, int n_in,
                              void* d_out, int out_size, void* d_ws, size_t ws_size,
                              hipStream_t stream) {
    const float* u        = (const float*)d_in[0];
    const float* features = (const float*)d_in[1];
    const float* bias     = (const float*)d_in[2];
    const float* w_in     = (const float*)d_in[3];
    const float* b_in     = (const float*)d_in[4];
    const float* sig_w1   = (const float*)d_in[5];
    const float* sig_b1   = (const float*)d_in[6];
    const float* sig_w2   = (const float*)d_in[7];
    const float* sig_b2   = (const float*)d_in[8];
    float* out = (float*)d_out;

    char*         ws     = (char*)d_ws;
    int*          idxT   = (int*)ws;                      // 51200 B
    float*        valsP  = (float*)(ws + 51200);          // 51200 B
    unsigned int* tbl    = (unsigned int*)(ws + 102400);  // 65536 B

    hipLaunchKernelGGL(pre_kernel, dim3(TOPK_BLKS + TBL_BLKS), dim3(256), 0, stream,
                       features, sig_w1, sig_b1, sig_w2, idxT, valsP, tbl);
    hipLaunchKernelGGL(steps_kernel, dim3(B_SZ / 2), dim3(1024), 0, stream,
                       u, w_in, b_in, bias, sig_b2, idxT, valsP, tbl, out);
}

// Round 19
// 90.637 us; speedup vs baseline: 1.3111x; 1.0745x over previous
//
#include <hip/hip_runtime.h>
#include <math.h>

#define N_NEU 256
#define D_DIM 32
#define KFD   16
#define KN    50
#define B_SZ  512
#define UINF  128
#define GAMMA 0.1f
#define DT    0.05f
#define NSTEP 20

// 4096-knot NEAREST-NEIGHBOR f32 table, Delta = 1/32, range [-64, +64).
// err <= Delta/2 * max|G'| ~ 9e-4/step -> <=0.02 accumulated (budget 0.196).
#define TBL_K   4096
#define TBL_LO  (-64.0f)
#define TBL_IDL 32.0f

#define TOPK_BLKS  N_NEU                 // 256
#define TBL_BLKS   (TBL_K * 32 / 256)    // 512

typedef __attribute__((ext_vector_type(8))) short bf16x8;
typedef __attribute__((ext_vector_type(4))) float f32x4;

__device__ __forceinline__ unsigned short f2bf(float f) {
    unsigned u = __float_as_uint(f);
    u += 0x7FFFu + ((u >> 16) & 1u);     // round-to-nearest-even
    return (unsigned short)(u >> 16);
}
__device__ __forceinline__ float bf_lo(unsigned q) { return __uint_as_float(q << 16); }
__device__ __forceinline__ float bf_hi(unsigned q) { return __uint_as_float(q & 0xFFFF0000u); }

// ---------------------------------------------------------------------------
// Kernel A: topk [0,256) + f32 table [256,768).
// vals ZERO-PADDED to 56 (4 subthreads x 14 k's) in pair layout:
//   float2 [jj][n*4+s], jj<7, covering k = s*14 + 2*jj + p.
// ---------------------------------------------------------------------------
__global__ __launch_bounds__(256) void pre_kernel(const float* __restrict__ features,
                                                  const float* __restrict__ sig_w1,
                                                  const float* __restrict__ sig_b1,
                                                  const float* __restrict__ sig_w2,
                                                  int* __restrict__ idxT,
                                                  float* __restrict__ vals2T,
                                                  float* __restrict__ tblf) {
    __shared__ float fsh[N_NEU][KFD + 1];
    __shared__ float sim_sh[N_NEU];

    const int bid = blockIdx.x;

    if (bid < TOPK_BLKS) {
        // ---- topk ----
        const int n = bid;
        const int j = threadIdx.x;

        float v[KFD];
        float s = 0.f;
#pragma unroll
        for (int d = 0; d < KFD; ++d) { v[d] = features[j * KFD + d]; s = fmaf(v[d], v[d], s); }
        const float nrm = sqrtf(s);
#pragma unroll
        for (int d = 0; d < KFD; ++d) fsh[j][d] = v[d] / nrm;
        __syncthreads();

        float dot = 0.f;
#pragma unroll
        for (int d = 0; d < KFD; ++d) dot = fmaf(fsh[n][d], fsh[j][d], dot);
        sim_sh[j] = dot;
        __syncthreads();

        if (j < 64) {
            float l0 = sim_sh[j];
            float l1 = sim_sh[j + 64];
            float l2 = sim_sh[j + 128];
            float l3 = sim_sh[j + 192];
            for (int k = 0; k < KN; ++k) {
                float bv = l0; int bi = j;
                if (l1 > bv) { bv = l1; bi = j + 64; }
                if (l2 > bv) { bv = l2; bi = j + 128; }
                if (l3 > bv) { bv = l3; bi = j + 192; }
                for (int off = 32; off > 0; off >>= 1) {
                    float ov = __shfl_xor(bv, off, 64);
                    int   oi = __shfl_xor(bi, off, 64);
                    if (ov > bv || (ov == bv && oi < bi)) { bv = ov; bi = oi; }
                }
                if (j == 0) {
                    const int s_ = k / 14;
                    const int r_ = k - 14 * s_;
                    vals2T[((r_ >> 1) * 1024 + n * 4 + s_) * 2 + (r_ & 1)] = bv;
                    idxT[k * N_NEU + n] = bi;
                }
                if ((bi & 63) == j) {
                    const int q = bi >> 6;
                    if      (q == 0) l0 = -INFINITY;
                    else if (q == 1) l1 = -INFINITY;
                    else if (q == 2) l2 = -INFINITY;
                    else             l3 = -INFINITY;
                }
            }
            if (j == 0) {   // zero-pad k = 50..55 (subthread 3, r = 8..13)
#pragma unroll
                for (int k = 50; k < 56; ++k) {
                    const int r_ = k - 42;
                    vals2T[((r_ >> 1) * 1024 + n * 4 + 3) * 2 + (r_ & 1)] = 0.f;
                }
            }
        }
    } else {
        // ---- f32 table: tblf[k*32+d] = DT * G_d(s_k) ----
        const int gid = (bid - TOPK_BLKS) * 256 + threadIdx.x;  // k*32+d
        const int k = gid >> 5, d = gid & 31;
        const float s0 = TBL_LO + (float)k / TBL_IDL;
        float g0 = 0.f;
#pragma unroll
        for (int j = 0; j < 16; ++j) {
            const float w1 = sig_w1[j], b1 = sig_b1[j], w2 = sig_w2[d * 16 + j];
            const float h0 = fmaf(s0, w1, b1);
            const float e0 = 0.5f * h0 * (1.0f + erff(h0 * 0.70710678118654752f));
            g0 = fmaf(e0, w2, g0);
        }
        tblf[gid] = DT * g0;
    }
}

// ---------------------------------------------------------------------------
// Kernel B: fused uproj-GEMM + 20-step recurrence — r12 structure verbatim
// (best measured total: 94.99 us) with ONE change: nearest-neighbor f32
// table apply (4 float4 loads + 16 adds, was lerp 32 fma + 16 bf16 unpacks;
// per-thread-step VALU ~125 -> ~95).
// w_in staged in LDS (wsh) as in r12; LDS = 8704 + 73728 + 2048 = 84480.
// ---------------------------------------------------------------------------
__global__ __launch_bounds__(1024) void steps_kernel(const float* __restrict__ u,
                                                     const float* __restrict__ w_in,
                                                     const float* __restrict__ b_in,
                                                     const float* __restrict__ bias,
                                                     const float* __restrict__ sig_b2,
                                                     const int* __restrict__ idxT,
                                                     const float* __restrict__ vals2T,
                                                     const float* __restrict__ tblf,
                                                     float* __restrict__ out) {
    __shared__ unsigned short wsh[32 * 136];       // bf16 w_in, row stride 136
    __shared__ float cdt_sh[2 * 256 * 36];         // 73728 B, row stride 36
    __shared__ unsigned int a_sh[2 * N_NEU];       // packed 2-batch bf16

    const int t = threadIdx.x;

    // ---- phase 0a: stage w_in -> LDS bf16 ----
    {
        const float4 w4 = reinterpret_cast<const float4*>(w_in)[t];
        const int d = t >> 5, k0 = (t & 31) * 4;
        unsigned short* wp = &wsh[d * 136 + k0];
        wp[0] = f2bf(w4.x); wp[1] = f2bf(w4.y); wp[2] = f2bf(w4.z); wp[3] = f2bf(w4.w);
    }
    __syncthreads();

    // ---- phase 0b: per-wave 32-row GEMM ----
    {
        const int wave = t >> 6;
        const int lane = t & 63;
        const int row  = lane & 15;
        const int kg   = lane >> 4;
        const int bb0  = wave >> 3;                    // which batch of the pair
        const int wrow = (wave & 7) * 32;              // first neuron row of wave
        const long bB  = (long)blockIdx.x * 2 + bb0;

        bf16x8 bfrag[2][4];
#pragma unroll
        for (int dt_ = 0; dt_ < 2; ++dt_)
#pragma unroll
            for (int kk = 0; kk < 4; ++kk)
                bfrag[dt_][kk] = *reinterpret_cast<const bf16x8*>(
                    &wsh[(dt_ * 16 + row) * 136 + kk * 32 + kg * 8]);

#pragma unroll
        for (int t4 = 0; t4 < 2; ++t4) {
            const float* ub = u + (bB * N_NEU + wrow + t4 * 16 + row) * UINF + kg * 8;
            float4 L[8];
#pragma unroll
            for (int kk = 0; kk < 4; ++kk) {
                L[kk * 2 + 0] = *reinterpret_cast<const float4*>(ub + kk * 32);
                L[kk * 2 + 1] = *reinterpret_cast<const float4*>(ub + kk * 32 + 4);
            }
            f32x4 a0 = {0.f, 0.f, 0.f, 0.f};
            f32x4 a1 = {0.f, 0.f, 0.f, 0.f};
#pragma unroll
            for (int kk = 0; kk < 4; ++kk) {
                bf16x8 af;
                const float4 x0 = L[kk * 2], x1 = L[kk * 2 + 1];
                af[0] = (short)f2bf(x0.x); af[1] = (short)f2bf(x0.y);
                af[2] = (short)f2bf(x0.z); af[3] = (short)f2bf(x0.w);
                af[4] = (short)f2bf(x1.x); af[5] = (short)f2bf(x1.y);
                af[6] = (short)f2bf(x1.z); af[7] = (short)f2bf(x1.w);
                a0 = __builtin_amdgcn_mfma_f32_16x16x32_bf16(af, bfrag[0][kk], a0, 0, 0, 0);
                a1 = __builtin_amdgcn_mfma_f32_16x16x32_bf16(af, bfrag[1][kk], a1, 0, 0, 0);
            }
            const int   d0   = row;
            const int   d1   = 16 + row;
            const float add0 = b_in[d0] + sig_b2[d0];
            const float add1 = b_in[d1] + sig_b2[d1];
#pragma unroll
            for (int r = 0; r < 4; ++r) {
                const int nl = wrow + t4 * 16 + kg * 4 + r;
                cdt_sh[bb0 * 9216 + nl * 36 + d0] = DT * (a0[r] + add0 + bias[nl * D_DIM + d0]);
                cdt_sh[bb0 * 9216 + nl * 36 + d1] = DT * (a1[r] + add1 + bias[nl * D_DIM + d1]);
            }
        }
    }
    __syncthreads();

    // ---- redistribute to per-thread ccdt regs ----
    const int n  = t >> 2;
    const int s  = t & 3;
    const int bb = s >> 1;
    const int h  = s & 1;
    const int b  = blockIdx.x * 2 + bb;

    float ccdt[16];
    {
        const float* cbase = &cdt_sh[bb * 9216 + n * 36 + h * 16];
#pragma unroll
        for (int i = 0; i < 4; ++i) {
            const float4 cv = *reinterpret_cast<const float4*>(cbase + i * 4);
            ccdt[4 * i + 0] = cv.x; ccdt[4 * i + 1] = cv.y;
            ccdt[4 * i + 2] = cv.z; ccdt[4 * i + 3] = cv.w;
        }
    }

    // ---- step-invariant per-thread vals + gather pointers ----
    const float2* v2g = reinterpret_cast<const float2*>(vals2T);
    float2 vv[7];
#pragma unroll
    for (int jj = 0; jj < 7; ++jj) vv[jj] = v2g[jj * 1024 + t];

    const unsigned int* gp[14];
#pragma unroll
    for (int j = 0; j < 14; ++j) {
        const int k = s * 14 + j;
        const int ii = (k < KN) ? idxT[k * N_NEU + n] : 0;
        gp[j] = &a_sh[ii];
    }

    float x[16];
#pragma unroll
    for (int d = 0; d < 16; ++d) x[d] = 0.f;

    const float K1 = 1.0f - DT * GAMMA;   // 0.995

#define STEP_BODY(BUF)                                                          \
    {                                                                           \
        float nh0 = 0.f, nh1 = 0.f;                                             \
        _Pragma("unroll")                                                       \
        for (int d = 0; d < 16; d += 2) {                                       \
            nh0 = fmaf(x[d], x[d], nh0);                                        \
            nh1 = fmaf(x[d + 1], x[d + 1], nh1);                                \
        }                                                                       \
        const float nh = nh0 + nh1;                                             \
        const float nfull = nh + __shfl_xor(nh, 1, 64) + 1e-12f;                \
        const float z = sqrtf(nfull);                                           \
        const float a = 1.0f - 2.0f / (__expf(2.0f * z) + 1.0f);                \
        const float ao = __shfl_xor(a, 2, 64);                                  \
        if (s == 0) a_sh[(BUF) * N_NEU + n] = (unsigned int)f2bf(a) | ((unsigned int)f2bf(ao) << 16); \
        _Pragma("unroll")                                                       \
        for (int d = 0; d < 16; ++d) x[d] = fmaf(K1, x[d], ccdt[d]);            \
        __syncthreads();                                                        \
        float sA0 = 0.f, sA1 = 0.f, sB0 = 0.f, sB1 = 0.f;                       \
        _Pragma("unroll")                                                       \
        for (int jj = 0; jj < 7; ++jj) {                                        \
            const unsigned int p0 = gp[2 * jj][(BUF) * N_NEU];                  \
            const unsigned int p1 = gp[2 * jj + 1][(BUF) * N_NEU];              \
            sA0 = fmaf(bf_lo(p0), vv[jj].x, sA0);                               \
            sB0 = fmaf(bf_hi(p0), vv[jj].x, sB0);                               \
            sA1 = fmaf(bf_lo(p1), vv[jj].y, sA1);                               \
            sB1 = fmaf(bf_hi(p1), vv[jj].y, sB1);                               \
        }                                                                       \
        float sA = sA0 + sA1;                                                   \
        float sB = sB0 + sB1;                                                   \
        sA += __shfl_xor(sA, 1, 64); sA += __shfl_xor(sA, 2, 64);               \
        sB += __shfl_xor(sB, 1, 64); sB += __shfl_xor(sB, 2, 64);               \
        const float syn = bb ? sB : sA;                                         \
        const float uu = fmaf(syn, TBL_IDL, 0.5f - TBL_LO * TBL_IDL);           \
        int i = (int)uu;   /* nearest knot (uu >= 0 after clamp range) */       \
        i = (i < 0) ? 0 : (i > TBL_K - 1 ? TBL_K - 1 : i);                      \
        const float4* rp = reinterpret_cast<const float4*>(tblf + (size_t)i * 32 + h * 16); \
        _Pragma("unroll")                                                       \
        for (int c = 0; c < 4; ++c) {                                           \
            const float4 q = rp[c];                                             \
            x[4 * c + 0] += q.x;                                                \
            x[4 * c + 1] += q.y;                                                \
            x[4 * c + 2] += q.z;                                                \
            x[4 * c + 3] += q.w;                                                \
        }                                                                       \
    }

    for (int it = 0; it < NSTEP / 2; ++it) {
        STEP_BODY(0);
        STEP_BODY(1);
    }
#undef STEP_BODY

    float4* op4 = reinterpret_cast<float4*>(out + ((size_t)b * N_NEU + n) * D_DIM + h * 16);
#pragma unroll
    for (int i = 0; i < 4; ++i)
        op4[i] = make_float4(x[4 * i + 0], x[4 * i + 1], x[4 * i + 2], x[4 * i + 3]);
}

extern "C" void kernel_launch(void* const* d_in, const int* in_sizes, int n_in,
                              void* d_out, int out_size, void* d_ws, size_t ws_size,
                              hipStream_t stream) {
    const float* u        = (const float*)d_in[0];
    const float* features = (const float*)d_in[1];
    const float* bias     = (const float*)d_in[2];
    const float* w_in     = (const float*)d_in[3];
    const float* b_in     = (const float*)d_in[4];
    const float* sig_w1   = (const float*)d_in[5];
    const float* sig_b1   = (const float*)d_in[6];
    const float* sig_w2   = (const float*)d_in[7];
    const float* sig_b2   = (const float*)d_in[8];
    float* out = (float*)d_out;

    char*  ws     = (char*)d_ws;
    int*   idxT   = (int*)ws;                      // 51200 B
    float* vals2T = (float*)(ws + 51200);          // 57344 B
    float* tblf   = (float*)(ws + 108544);         // 4096*32*4 = 524288 B

    hipLaunchKernelGGL(pre_kernel, dim3(TOPK_BLKS + TBL_BLKS), dim3(256), 0, stream,
                       features, sig_w1, sig_b1, sig_w2, idxT, vals2T, tblf);
    hipLaunchKernelGGL(steps_kernel, dim3(B_SZ / 2), dim3(1024), 0, stream,
                       u, w_in, b_in, bias, sig_b2, idxT, vals2T, tblf, out);
}

// Round 20
// 61.137 us; speedup vs baseline: 1.9437x; 1.4825x over previous
//
#include <hip/hip_runtime.h>
#include <math.h>

#define N_NEU 256
#define D_DIM 32
#define KFD   16
#define KN    50
#define B_SZ  512
#define UINF  128
#define GAMMA 0.1f
#define DT    0.05f
#define NSTEP 20

// 4096-knot NEAREST-NEIGHBOR f32 table, Delta = 1/32, range [-64, +64).
#define TBL_K   4096
#define TBL_LO  (-64.0f)
#define TBL_IDL 32.0f

#define TOPK_BLKS  N_NEU                 // 256
#define TBL_BLKS   (TBL_K * 32 / 256)    // 512

typedef __attribute__((ext_vector_type(8))) short bf16x8;
typedef __attribute__((ext_vector_type(4))) float f32x4;

__device__ __forceinline__ unsigned short f2bf(float f) {
    unsigned u = __float_as_uint(f);
    u += 0x7FFFu + ((u >> 16) & 1u);     // round-to-nearest-even
    return (unsigned short)(u >> 16);
}
__device__ __forceinline__ float bf_lo(unsigned q) { return __uint_as_float(q << 16); }
__device__ __forceinline__ float bf_hi(unsigned q) { return __uint_as_float(q & 0xFFFF0000u); }

// ---------------------------------------------------------------------------
// Kernel A: topk [0,256) + f32 table [256,768).
// topk via RANK-PARALLEL selection (r19's 50-iter serial shuffle-argmax was
// an ~10us latency chain on one wave): element j's output position is
//   rank(j) = #{ i : sim[i]>sim[j] || (sim[i]==sim[j] && i<j) }
// which equals jax.lax.top_k's descending order w/ lowest-index tie-break.
// All 256 threads rank in parallel via same-address LDS broadcasts.
// vals ZERO-PADDED to 56 in pair layout float2 [jj][n*4+s], jj<7,
// covering k = s*14 + 2*jj + p.
// ---------------------------------------------------------------------------
__global__ __launch_bounds__(256) void pre_kernel(const float* __restrict__ features,
                                                  const float* __restrict__ sig_w1,
                                                  const float* __restrict__ sig_b1,
                                                  const float* __restrict__ sig_w2,
                                                  int* __restrict__ idxT,
                                                  float* __restrict__ vals2T,
                                                  float* __restrict__ tblf) {
    __shared__ float fsh[N_NEU][KFD + 1];
    __shared__ float sim_sh[N_NEU];

    const int bid = blockIdx.x;

    if (bid < TOPK_BLKS) {
        // ---- topk ----
        const int n = bid;
        const int j = threadIdx.x;

        float v[KFD];
        float s = 0.f;
#pragma unroll
        for (int d = 0; d < KFD; ++d) { v[d] = features[j * KFD + d]; s = fmaf(v[d], v[d], s); }
        const float nrm = sqrtf(s);
#pragma unroll
        for (int d = 0; d < KFD; ++d) fsh[j][d] = v[d] / nrm;
        __syncthreads();

        float dot = 0.f;
#pragma unroll
        for (int d = 0; d < KFD; ++d) dot = fmaf(fsh[n][d], fsh[j][d], dot);
        sim_sh[j] = dot;
        __syncthreads();

        // rank-parallel selection: all threads count in parallel;
        // sim_sh[i] is a same-address broadcast per iteration (conflict-free)
        const float my = dot;
        int rank = 0;
#pragma unroll 8
        for (int i = 0; i < N_NEU; ++i) {
            const float si = sim_sh[i];
            rank += (si > my || (si == my && i < j)) ? 1 : 0;
        }
        if (rank < KN) {
            const int s_ = rank / 14;              // compile-time-const divisor
            const int r_ = rank - 14 * s_;
            vals2T[((r_ >> 1) * 1024 + n * 4 + s_) * 2 + (r_ & 1)] = my;
            idxT[rank * N_NEU + n] = j;
        }
        if (j == 0) {   // zero-pad k = 50..55 (subthread 3, r = 8..13)
#pragma unroll
            for (int k = 50; k < 56; ++k) {
                const int r_ = k - 42;
                vals2T[((r_ >> 1) * 1024 + n * 4 + 3) * 2 + (r_ & 1)] = 0.f;
            }
        }
    } else {
        // ---- f32 table: tblf[k*32+d] = DT * G_d(s_k) ----
        const int gid = (bid - TOPK_BLKS) * 256 + threadIdx.x;  // k*32+d
        const int k = gid >> 5, d = gid & 31;
        const float s0 = TBL_LO + (float)k / TBL_IDL;
        float g0 = 0.f;
#pragma unroll
        for (int j = 0; j < 16; ++j) {
            const float w1 = sig_w1[j], b1 = sig_b1[j], w2 = sig_w2[d * 16 + j];
            const float h0 = fmaf(s0, w1, b1);
            const float e0 = 0.5f * h0 * (1.0f + erff(h0 * 0.70710678118654752f));
            g0 = fmaf(e0, w2, g0);
        }
        tblf[gid] = DT * g0;
    }
}

// ---------------------------------------------------------------------------
// Kernel B: fused uproj-GEMM + 20-step recurrence (r19 structure = best
// measured, 90.6us total) with one micro-opt: tanh via single-instruction
// exp2/rcp intrinsics (removes the IEEE-divide sequence from the per-step
// serial chain).  LDS = 8704 + 73728 + 2048 = 84480.
// ---------------------------------------------------------------------------
__global__ __launch_bounds__(1024) void steps_kernel(const float* __restrict__ u,
                                                     const float* __restrict__ w_in,
                                                     const float* __restrict__ b_in,
                                                     const float* __restrict__ bias,
                                                     const float* __restrict__ sig_b2,
                                                     const int* __restrict__ idxT,
                                                     const float* __restrict__ vals2T,
                                                     const float* __restrict__ tblf,
                                                     float* __restrict__ out) {
    __shared__ unsigned short wsh[32 * 136];       // bf16 w_in, row stride 136
    __shared__ float cdt_sh[2 * 256 * 36];         // 73728 B, row stride 36
    __shared__ unsigned int a_sh[2 * N_NEU];       // packed 2-batch bf16

    const int t = threadIdx.x;

    // ---- phase 0a: stage w_in -> LDS bf16 ----
    {
        const float4 w4 = reinterpret_cast<const float4*>(w_in)[t];
        const int d = t >> 5, k0 = (t & 31) * 4;
        unsigned short* wp = &wsh[d * 136 + k0];
        wp[0] = f2bf(w4.x); wp[1] = f2bf(w4.y); wp[2] = f2bf(w4.z); wp[3] = f2bf(w4.w);
    }
    __syncthreads();

    // ---- phase 0b: per-wave 32-row GEMM ----
    {
        const int wave = t >> 6;
        const int lane = t & 63;
        const int row  = lane & 15;
        const int kg   = lane >> 4;
        const int bb0  = wave >> 3;                    // which batch of the pair
        const int wrow = (wave & 7) * 32;              // first neuron row of wave
        const long bB  = (long)blockIdx.x * 2 + bb0;

        bf16x8 bfrag[2][4];
#pragma unroll
        for (int dt_ = 0; dt_ < 2; ++dt_)
#pragma unroll
            for (int kk = 0; kk < 4; ++kk)
                bfrag[dt_][kk] = *reinterpret_cast<const bf16x8*>(
                    &wsh[(dt_ * 16 + row) * 136 + kk * 32 + kg * 8]);

#pragma unroll
        for (int t4 = 0; t4 < 2; ++t4) {
            const float* ub = u + (bB * N_NEU + wrow + t4 * 16 + row) * UINF + kg * 8;
            float4 L[8];
#pragma unroll
            for (int kk = 0; kk < 4; ++kk) {
                L[kk * 2 + 0] = *reinterpret_cast<const float4*>(ub + kk * 32);
                L[kk * 2 + 1] = *reinterpret_cast<const float4*>(ub + kk * 32 + 4);
            }
            f32x4 a0 = {0.f, 0.f, 0.f, 0.f};
            f32x4 a1 = {0.f, 0.f, 0.f, 0.f};
#pragma unroll
            for (int kk = 0; kk < 4; ++kk) {
                bf16x8 af;
                const float4 x0 = L[kk * 2], x1 = L[kk * 2 + 1];
                af[0] = (short)f2bf(x0.x); af[1] = (short)f2bf(x0.y);
                af[2] = (short)f2bf(x0.z); af[3] = (short)f2bf(x0.w);
                af[4] = (short)f2bf(x1.x); af[5] = (short)f2bf(x1.y);
                af[6] = (short)f2bf(x1.z); af[7] = (short)f2bf(x1.w);
                a0 = __builtin_amdgcn_mfma_f32_16x16x32_bf16(af, bfrag[0][kk], a0, 0, 0, 0);
                a1 = __builtin_amdgcn_mfma_f32_16x16x32_bf16(af, bfrag[1][kk], a1, 0, 0, 0);
            }
            const int   d0   = row;
            const int   d1   = 16 + row;
            const float add0 = b_in[d0] + sig_b2[d0];
            const float add1 = b_in[d1] + sig_b2[d1];
#pragma unroll
            for (int r = 0; r < 4; ++r) {
                const int nl = wrow + t4 * 16 + kg * 4 + r;
                cdt_sh[bb0 * 9216 + nl * 36 + d0] = DT * (a0[r] + add0 + bias[nl * D_DIM + d0]);
                cdt_sh[bb0 * 9216 + nl * 36 + d1] = DT * (a1[r] + add1 + bias[nl * D_DIM + d1]);
            }
        }
    }
    __syncthreads();

    // ---- redistribute to per-thread ccdt regs ----
    const int n  = t >> 2;
    const int s  = t & 3;
    const int bb = s >> 1;
    const int h  = s & 1;
    const int b  = blockIdx.x * 2 + bb;

    float ccdt[16];
    {
        const float* cbase = &cdt_sh[bb * 9216 + n * 36 + h * 16];
#pragma unroll
        for (int i = 0; i < 4; ++i) {
            const float4 cv = *reinterpret_cast<const float4*>(cbase + i * 4);
            ccdt[4 * i + 0] = cv.x; ccdt[4 * i + 1] = cv.y;
            ccdt[4 * i + 2] = cv.z; ccdt[4 * i + 3] = cv.w;
        }
    }

    // ---- step-invariant per-thread vals + gather pointers ----
    const float2* v2g = reinterpret_cast<const float2*>(vals2T);
    float2 vv[7];
#pragma unroll
    for (int jj = 0; jj < 7; ++jj) vv[jj] = v2g[jj * 1024 + t];

    const unsigned int* gp[14];
#pragma unroll
    for (int j = 0; j < 14; ++j) {
        const int k = s * 14 + j;
        const int ii = (k < KN) ? idxT[k * N_NEU + n] : 0;
        gp[j] = &a_sh[ii];
    }

    float x[16];
#pragma unroll
    for (int d = 0; d < 16; ++d) x[d] = 0.f;

    const float K1 = 1.0f - DT * GAMMA;      // 0.995
    const float L2E2 = 2.8853900817779268f;  // 2*log2(e)

#define STEP_BODY(BUF)                                                          \
    {                                                                           \
        float nh0 = 0.f, nh1 = 0.f;                                             \
        _Pragma("unroll")                                                       \
        for (int d = 0; d < 16; d += 2) {                                       \
            nh0 = fmaf(x[d], x[d], nh0);                                        \
            nh1 = fmaf(x[d + 1], x[d + 1], nh1);                                \
        }                                                                       \
        const float nh = nh0 + nh1;                                             \
        const float nfull = nh + __shfl_xor(nh, 1, 64) + 1e-12f;                \
        const float z = sqrtf(nfull);                                           \
        /* tanh(z) = 1 - 2/(exp(2z)+1) via single-inst exp2 + rcp */            \
        const float e2 = __builtin_amdgcn_exp2f(L2E2 * z);                      \
        const float a = fmaf(-2.0f, __builtin_amdgcn_rcpf(e2 + 1.0f), 1.0f);    \
        const float ao = __shfl_xor(a, 2, 64);                                  \
        if (s == 0) a_sh[(BUF) * N_NEU + n] = (unsigned int)f2bf(a) | ((unsigned int)f2bf(ao) << 16); \
        _Pragma("unroll")                                                       \
        for (int d = 0; d < 16; ++d) x[d] = fmaf(K1, x[d], ccdt[d]);            \
        __syncthreads();                                                        \
        float sA0 = 0.f, sA1 = 0.f, sB0 = 0.f, sB1 = 0.f;                       \
        _Pragma("unroll")                                                       \
        for (int jj = 0; jj < 7; ++jj) {                                        \
            const unsigned int p0 = gp[2 * jj][(BUF) * N_NEU];                  \
            const unsigned int p1 = gp[2 * jj + 1][(BUF) * N_NEU];              \
            sA0 = fmaf(bf_lo(p0), vv[jj].x, sA0);                               \
            sB0 = fmaf(bf_hi(p0), vv[jj].x, sB0);                               \
            sA1 = fmaf(bf_lo(p1), vv[jj].y, sA1);                               \
            sB1 = fmaf(bf_hi(p1), vv[jj].y, sB1);                               \
        }                                                                       \
        float sA = sA0 + sA1;                                                   \
        float sB = sB0 + sB1;                                                   \
        sA += __shfl_xor(sA, 1, 64); sA += __shfl_xor(sA, 2, 64);               \
        sB += __shfl_xor(sB, 1, 64); sB += __shfl_xor(sB, 2, 64);               \
        const float syn = bb ? sB : sA;                                         \
        const float uu = fmaf(syn, TBL_IDL, 0.5f - TBL_LO * TBL_IDL);           \
        int i = (int)uu;   /* nearest knot */                                   \
        i = (i < 0) ? 0 : (i > TBL_K - 1 ? TBL_K - 1 : i);                      \
        const float4* rp = reinterpret_cast<const float4*>(tblf + (size_t)i * 32 + h * 16); \
        _Pragma("unroll")                                                       \
        for (int c = 0; c < 4; ++c) {                                           \
            const float4 q = rp[c];                                             \
            x[4 * c + 0] += q.x;                                                \
            x[4 * c + 1] += q.y;                                                \
            x[4 * c + 2] += q.z;                                                \
            x[4 * c + 3] += q.w;                                                \
        }                                                                       \
    }

    for (int it = 0; it < NSTEP / 2; ++it) {
        STEP_BODY(0);
        STEP_BODY(1);
    }
#undef STEP_BODY

    float4* op4 = reinterpret_cast<float4*>(out + ((size_t)b * N_NEU + n) * D_DIM + h * 16);
#pragma unroll
    for (int i = 0; i < 4; ++i)
        op4[i] = make_float4(x[4 * i + 0], x[4 * i + 1], x[4 * i + 2], x[4 * i + 3]);
}

extern "C" void kernel_launch(void* const* d_in, const int* in_sizes, int n_in,
                              void* d_out, int out_size, void* d_ws, size_t ws_size,
                              hipStream_t stream) {
    const float* u        = (const float*)d_in[0];
    const float* features = (const float*)d_in[1];
    const float* bias     = (const float*)d_in[2];
    const float* w_in     = (const float*)d_in[3];
    const float* b_in     = (const float*)d_in[4];
    const float* sig_w1   = (const float*)d_in[5];
    const float* sig_b1   = (const float*)d_in[6];
    const float* sig_w2   = (const float*)d_in[7];
    const float* sig_b2   = (const float*)d_in[8];
    float* out = (float*)d_out;

    char*  ws     = (char*)d_ws;
    int*   idxT   = (int*)ws;                      // 51200 B
    float* vals2T = (float*)(ws + 51200);          // 57344 B
    float* tblf   = (float*)(ws + 108544);         // 524288 B

    hipLaunchKernelGGL(pre_kernel, dim3(TOPK_BLKS + TBL_BLKS), dim3(256), 0, stream,
                       features, sig_w1, sig_b1, sig_w2, idxT, vals2T, tblf);
    hipLaunchKernelGGL(steps_kernel, dim3(B_SZ / 2), dim3(1024), 0, stream,
                       u, w_in, b_in, bias, sig_b2, idxT, vals2T, tblf, out);
}

// Round 21
// 59.870 us; speedup vs baseline: 1.9848x; 1.0212x over previous
//
#include <hip/hip_runtime.h>
#include <math.h>

#define N_NEU 256
#define D_DIM 32
#define KFD   16
#define KN    50
#define B_SZ  512
#define UINF  128
#define GAMMA 0.1f
#define DT    0.05f
#define NSTEP 20

// 4096-knot NEAREST-NEIGHBOR bf16 table, Delta = 1/32, range [-64, +64).
// NN err ~9e-4/step + bf16 quant ~1e-4/step -> <=0.03 accumulated (budget 0.196).
#define TBL_K   4096
#define TBL_LO  (-64.0f)
#define TBL_IDL 32.0f

#define TOPK_BLKS  N_NEU                 // 256
#define TBL_BLKS   (TBL_K * 16 / 256)    // 256 (packed: 16 u32 per knot)

typedef __attribute__((ext_vector_type(8))) short bf16x8;
typedef __attribute__((ext_vector_type(4))) float f32x4;

__device__ __forceinline__ unsigned short f2bf(float f) {
    unsigned u = __float_as_uint(f);
    u += 0x7FFFu + ((u >> 16) & 1u);     // round-to-nearest-even
    return (unsigned short)(u >> 16);
}
__device__ __forceinline__ float bf_lo(unsigned q) { return __uint_as_float(q << 16); }
__device__ __forceinline__ float bf_hi(unsigned q) { return __uint_as_float(q & 0xFFFF0000u); }

// ---------------------------------------------------------------------------
// Kernel A: topk [0,256) + packed-bf16 table [256,512).
// topk via rank-parallel selection (r20, verified): element j's output
// position = #{i : sim[i]>sim[j] || (sim[i]==sim[j] && i<j)} — equals
// jax.lax.top_k descending order with lowest-index tie-break.
// vals ZERO-PADDED to 56 in pair layout float2 [jj][n*4+s], jj<7,
// covering k = s*14 + 2*jj + p.
// ---------------------------------------------------------------------------
__global__ __launch_bounds__(256) void pre_kernel(const float* __restrict__ features,
                                                  const float* __restrict__ sig_w1,
                                                  const float* __restrict__ sig_b1,
                                                  const float* __restrict__ sig_w2,
                                                  int* __restrict__ idxT,
                                                  float* __restrict__ vals2T,
                                                  unsigned int* __restrict__ tblb) {
    __shared__ float fsh[N_NEU][KFD + 1];
    __shared__ float sim_sh[N_NEU];

    const int bid = blockIdx.x;

    if (bid < TOPK_BLKS) {
        // ---- topk ----
        const int n = bid;
        const int j = threadIdx.x;

        float v[KFD];
        float s = 0.f;
#pragma unroll
        for (int d = 0; d < KFD; ++d) { v[d] = features[j * KFD + d]; s = fmaf(v[d], v[d], s); }
        const float nrm = sqrtf(s);
#pragma unroll
        for (int d = 0; d < KFD; ++d) fsh[j][d] = v[d] / nrm;
        __syncthreads();

        float dot = 0.f;
#pragma unroll
        for (int d = 0; d < KFD; ++d) dot = fmaf(fsh[n][d], fsh[j][d], dot);
        sim_sh[j] = dot;
        __syncthreads();

        const float my = dot;
        int rank = 0;
#pragma unroll 8
        for (int i = 0; i < N_NEU; ++i) {
            const float si = sim_sh[i];
            rank += (si > my || (si == my && i < j)) ? 1 : 0;
        }
        if (rank < KN) {
            const int s_ = rank / 14;
            const int r_ = rank - 14 * s_;
            vals2T[((r_ >> 1) * 1024 + n * 4 + s_) * 2 + (r_ & 1)] = my;
            idxT[rank * N_NEU + n] = j;
        }
        if (j == 0) {   // zero-pad k = 50..55 (subthread 3, r = 8..13)
#pragma unroll
            for (int k = 50; k < 56; ++k) {
                const int r_ = k - 42;
                vals2T[((r_ >> 1) * 1024 + n * 4 + 3) * 2 + (r_ & 1)] = 0.f;
            }
        }
    } else {
        // ---- packed bf16 table: tblb[k*16+p] = bf16(DT*G_{2p}) | bf16(DT*G_{2p+1})<<16
        const int gid = (bid - TOPK_BLKS) * 256 + threadIdx.x;  // k*16+p
        const int k = gid >> 4, p = gid & 15;
        const int d0 = 2 * p, d1 = 2 * p + 1;
        const float s0 = TBL_LO + (float)k / TBL_IDL;
        float g0 = 0.f, g1 = 0.f;
#pragma unroll
        for (int j = 0; j < 16; ++j) {
            const float w1 = sig_w1[j], b1 = sig_b1[j];
            const float h0 = fmaf(s0, w1, b1);
            const float e0 = 0.5f * h0 * (1.0f + erff(h0 * 0.70710678118654752f));
            g0 = fmaf(e0, sig_w2[d0 * 16 + j], g0);
            g1 = fmaf(e0, sig_w2[d1 * 16 + j], g1);
        }
        g0 *= DT; g1 *= DT;
        tblb[gid] = (unsigned int)f2bf(g0) | ((unsigned int)f2bf(g1) << 16);
    }
}

// ---------------------------------------------------------------------------
// Kernel B: fused uproj-GEMM + 20-step recurrence (r20 structure = best
// measured, 61.1us total). One change: packed-bf16 NN table (2 uint4 loads
// = 32B/thread/step, was 64B f32) — halves the ~1000cyc/step L2 table
// component for +2 VALU/dim unpack on the least-busy pipe.
// LDS = 8704 + 73728 + 2048 = 84480.
// ---------------------------------------------------------------------------
__global__ __launch_bounds__(1024) void steps_kernel(const float* __restrict__ u,
                                                     const float* __restrict__ w_in,
                                                     const float* __restrict__ b_in,
                                                     const float* __restrict__ bias,
                                                     const float* __restrict__ sig_b2,
                                                     const int* __restrict__ idxT,
                                                     const float* __restrict__ vals2T,
                                                     const unsigned int* __restrict__ tblb,
                                                     float* __restrict__ out) {
    __shared__ unsigned short wsh[32 * 136];       // bf16 w_in, row stride 136
    __shared__ float cdt_sh[2 * 256 * 36];         // 73728 B, row stride 36
    __shared__ unsigned int a_sh[2 * N_NEU];       // packed 2-batch bf16

    const int t = threadIdx.x;

    // ---- phase 0a: stage w_in -> LDS bf16 ----
    {
        const float4 w4 = reinterpret_cast<const float4*>(w_in)[t];
        const int d = t >> 5, k0 = (t & 31) * 4;
        unsigned short* wp = &wsh[d * 136 + k0];
        wp[0] = f2bf(w4.x); wp[1] = f2bf(w4.y); wp[2] = f2bf(w4.z); wp[3] = f2bf(w4.w);
    }
    __syncthreads();

    // ---- phase 0b: per-wave 32-row GEMM ----
    {
        const int wave = t >> 6;
        const int lane = t & 63;
        const int row  = lane & 15;
        const int kg   = lane >> 4;
        const int bb0  = wave >> 3;                    // which batch of the pair
        const int wrow = (wave & 7) * 32;              // first neuron row of wave
        const long bB  = (long)blockIdx.x * 2 + bb0;

        bf16x8 bfrag[2][4];
#pragma unroll
        for (int dt_ = 0; dt_ < 2; ++dt_)
#pragma unroll
            for (int kk = 0; kk < 4; ++kk)
                bfrag[dt_][kk] = *reinterpret_cast<const bf16x8*>(
                    &wsh[(dt_ * 16 + row) * 136 + kk * 32 + kg * 8]);

#pragma unroll
        for (int t4 = 0; t4 < 2; ++t4) {
            const float* ub = u + (bB * N_NEU + wrow + t4 * 16 + row) * UINF + kg * 8;
            float4 L[8];
#pragma unroll
            for (int kk = 0; kk < 4; ++kk) {
                L[kk * 2 + 0] = *reinterpret_cast<const float4*>(ub + kk * 32);
                L[kk * 2 + 1] = *reinterpret_cast<const float4*>(ub + kk * 32 + 4);
            }
            f32x4 a0 = {0.f, 0.f, 0.f, 0.f};
            f32x4 a1 = {0.f, 0.f, 0.f, 0.f};
#pragma unroll
            for (int kk = 0; kk < 4; ++kk) {
                bf16x8 af;
                const float4 x0 = L[kk * 2], x1 = L[kk * 2 + 1];
                af[0] = (short)f2bf(x0.x); af[1] = (short)f2bf(x0.y);
                af[2] = (short)f2bf(x0.z); af[3] = (short)f2bf(x0.w);
                af[4] = (short)f2bf(x1.x); af[5] = (short)f2bf(x1.y);
                af[6] = (short)f2bf(x1.z); af[7] = (short)f2bf(x1.w);
                a0 = __builtin_amdgcn_mfma_f32_16x16x32_bf16(af, bfrag[0][kk], a0, 0, 0, 0);
                a1 = __builtin_amdgcn_mfma_f32_16x16x32_bf16(af, bfrag[1][kk], a1, 0, 0, 0);
            }
            const int   d0   = row;
            const int   d1   = 16 + row;
            const float add0 = b_in[d0] + sig_b2[d0];
            const float add1 = b_in[d1] + sig_b2[d1];
#pragma unroll
            for (int r = 0; r < 4; ++r) {
                const int nl = wrow + t4 * 16 + kg * 4 + r;
                cdt_sh[bb0 * 9216 + nl * 36 + d0] = DT * (a0[r] + add0 + bias[nl * D_DIM + d0]);
                cdt_sh[bb0 * 9216 + nl * 36 + d1] = DT * (a1[r] + add1 + bias[nl * D_DIM + d1]);
            }
        }
    }
    __syncthreads();

    // ---- redistribute to per-thread ccdt regs ----
    const int n  = t >> 2;
    const int s  = t & 3;
    const int bb = s >> 1;
    const int h  = s & 1;
    const int b  = blockIdx.x * 2 + bb;

    float ccdt[16];
    {
        const float* cbase = &cdt_sh[bb * 9216 + n * 36 + h * 16];
#pragma unroll
        for (int i = 0; i < 4; ++i) {
            const float4 cv = *reinterpret_cast<const float4*>(cbase + i * 4);
            ccdt[4 * i + 0] = cv.x; ccdt[4 * i + 1] = cv.y;
            ccdt[4 * i + 2] = cv.z; ccdt[4 * i + 3] = cv.w;
        }
    }

    // ---- step-invariant per-thread vals + gather pointers ----
    const float2* v2g = reinterpret_cast<const float2*>(vals2T);
    float2 vv[7];
#pragma unroll
    for (int jj = 0; jj < 7; ++jj) vv[jj] = v2g[jj * 1024 + t];

    const unsigned int* gp[14];
#pragma unroll
    for (int j = 0; j < 14; ++j) {
        const int k = s * 14 + j;
        const int ii = (k < KN) ? idxT[k * N_NEU + n] : 0;
        gp[j] = &a_sh[ii];
    }

    float x[16];
#pragma unroll
    for (int d = 0; d < 16; ++d) x[d] = 0.f;

    const float K1 = 1.0f - DT * GAMMA;      // 0.995
    const float L2E2 = 2.8853900817779268f;  // 2*log2(e)

#define STEP_BODY(BUF)                                                          \
    {                                                                           \
        float nh0 = 0.f, nh1 = 0.f;                                             \
        _Pragma("unroll")                                                       \
        for (int d = 0; d < 16; d += 2) {                                       \
            nh0 = fmaf(x[d], x[d], nh0);                                        \
            nh1 = fmaf(x[d + 1], x[d + 1], nh1);                                \
        }                                                                       \
        const float nh = nh0 + nh1;                                             \
        const float nfull = nh + __shfl_xor(nh, 1, 64) + 1e-12f;                \
        const float z = sqrtf(nfull);                                           \
        const float e2 = __builtin_amdgcn_exp2f(L2E2 * z);                      \
        const float a = fmaf(-2.0f, __builtin_amdgcn_rcpf(e2 + 1.0f), 1.0f);    \
        const float ao = __shfl_xor(a, 2, 64);                                  \
        if (s == 0) a_sh[(BUF) * N_NEU + n] = (unsigned int)f2bf(a) | ((unsigned int)f2bf(ao) << 16); \
        _Pragma("unroll")                                                       \
        for (int d = 0; d < 16; ++d) x[d] = fmaf(K1, x[d], ccdt[d]);            \
        __syncthreads();                                                        \
        float sA0 = 0.f, sA1 = 0.f, sB0 = 0.f, sB1 = 0.f;                       \
        _Pragma("unroll")                                                       \
        for (int jj = 0; jj < 7; ++jj) {                                        \
            const unsigned int p0 = gp[2 * jj][(BUF) * N_NEU];                  \
            const unsigned int p1 = gp[2 * jj + 1][(BUF) * N_NEU];              \
            sA0 = fmaf(bf_lo(p0), vv[jj].x, sA0);                               \
            sB0 = fmaf(bf_hi(p0), vv[jj].x, sB0);                               \
            sA1 = fmaf(bf_lo(p1), vv[jj].y, sA1);                               \
            sB1 = fmaf(bf_hi(p1), vv[jj].y, sB1);                               \
        }                                                                       \
        float sA = sA0 + sA1;                                                   \
        float sB = sB0 + sB1;                                                   \
        sA += __shfl_xor(sA, 1, 64); sA += __shfl_xor(sA, 2, 64);               \
        sB += __shfl_xor(sB, 1, 64); sB += __shfl_xor(sB, 2, 64);               \
        const float syn = bb ? sB : sA;                                         \
        const float uu = fmaf(syn, TBL_IDL, 0.5f - TBL_LO * TBL_IDL);           \
        int i = (int)uu;   /* nearest knot */                                   \
        i = (i < 0) ? 0 : (i > TBL_K - 1 ? TBL_K - 1 : i);                      \
        const uint4* rp = reinterpret_cast<const uint4*>(tblb + (size_t)i * 16 + h * 8); \
        _Pragma("unroll")                                                       \
        for (int c = 0; c < 2; ++c) {                                           \
            const uint4 q = rp[c];                                              \
            x[8 * c + 0] += bf_lo(q.x);                                         \
            x[8 * c + 1] += bf_hi(q.x);                                         \
            x[8 * c + 2] += bf_lo(q.y);                                         \
            x[8 * c + 3] += bf_hi(q.y);                                         \
            x[8 * c + 4] += bf_lo(q.z);                                         \
            x[8 * c + 5] += bf_hi(q.z);                                         \
            x[8 * c + 6] += bf_lo(q.w);                                         \
            x[8 * c + 7] += bf_hi(q.w);                                         \
        }                                                                       \
    }

    for (int it = 0; it < NSTEP / 2; ++it) {
        STEP_BODY(0);
        STEP_BODY(1);
    }
#undef STEP_BODY

    float4* op4 = reinterpret_cast<float4*>(out + ((size_t)b * N_NEU + n) * D_DIM + h * 16);
#pragma unroll
    for (int i = 0; i < 4; ++i)
        op4[i] = make_float4(x[4 * i + 0], x[4 * i + 1], x[4 * i + 2], x[4 * i + 3]);
}

extern "C" void kernel_launch(void* const* d_in, const int* in_sizes, int n_in,
                              void* d_out, int out_size, void* d_ws, size_t ws_size,
                              hipStream_t stream) {
    const float* u        = (const float*)d_in[0];
    const float* features = (const float*)d_in[1];
    const float* bias     = (const float*)d_in[2];
    const float* w_in     = (const float*)d_in[3];
    const float* b_in     = (const float*)d_in[4];
    const float* sig_w1   = (const float*)d_in[5];
    const float* sig_b1   = (const float*)d_in[6];
    const float* sig_w2   = (const float*)d_in[7];
    const float* sig_b2   = (const float*)d_in[8];
    float* out = (float*)d_out;

    char*         ws     = (char*)d_ws;
    int*          idxT   = (int*)ws;                      // 51200 B
    float*        vals2T = (float*)(ws + 51200);          // 57344 B
    unsigned int* tblb   = (unsigned int*)(ws + 108544);  // 4096*16*4 = 262144 B

    hipLaunchKernelGGL(pre_kernel, dim3(TOPK_BLKS + TBL_BLKS), dim3(256), 0, stream,
                       features, sig_w1, sig_b1, sig_w2, idxT, vals2T, tblb);
    hipLaunchKernelGGL(steps_kernel, dim3(B_SZ / 2), dim3(1024), 0, stream,
                       u, w_in, b_in, bias, sig_b2, idxT, vals2T, tblb, out);
}